// Round 1
// baseline (3444.483 us; speedup 1.0000x reference)
//
#include <hip/hip_runtime.h>
#include <hip/hip_bf16.h>

#define HDIM 256
#define IDIM 512
#define NST 16
#define KCONV 4
#define LAYERS 4
#define BATCH 4
#define LSEQ 1024
#define TOK (BATCH * LSEQ)   // 4096

// -------------------- embedding --------------------
__global__ __launch_bounds__(256) void embed_kernel(const int* __restrict__ ids,
                                                    const float* __restrict__ embed,
                                                    float* __restrict__ h) {
    int idx = blockIdx.x * 256 + threadIdx.x;          // TOK*HDIM = 1,048,576
    if (idx < TOK * HDIM) {
        int tok = idx >> 8;
        int c = idx & (HDIM - 1);
        h[idx] = embed[ids[tok] * HDIM + c];
    }
}

// -------------------- rmsnorm (per token row of H=256) --------------------
__global__ __launch_bounds__(256) void rmsnorm_kernel(const float* __restrict__ h,
                                                      const float* __restrict__ w,
                                                      float* __restrict__ x) {
    int tok = blockIdx.x;
    int c = threadIdx.x;
    float v = h[tok * HDIM + c];
    float s = v * v;
    #pragma unroll
    for (int m = 32; m >= 1; m >>= 1) s += __shfl_xor(s, m, 64);
    __shared__ float ls[4];
    __shared__ float rstd_s;
    int wid = threadIdx.x >> 6;
    if ((threadIdx.x & 63) == 0) ls[wid] = s;
    __syncthreads();
    if (threadIdx.x == 0) {
        float tot = ls[0] + ls[1] + ls[2] + ls[3];
        rstd_s = rsqrtf(tot * (1.0f / HDIM) + 1e-5f);
    }
    __syncthreads();
    x[tok * HDIM + c] = v * rstd_s * w[c];
}

// -------------------- generic tiled GEMM: C[M,N] = A[M,K(lda)] * W[N,K]^T --------------------
// EPI: 0 = store, 1 = accumulate into C (residual), 2 = softplus(acc + bias)
template <int EPI>
__global__ __launch_bounds__(256) void gemm_kernel(const float* __restrict__ A,
                                                   const float* __restrict__ W,
                                                   const float* __restrict__ bias,
                                                   float* __restrict__ C,
                                                   int M, int N, int K, int lda) {
    const int BM = 64, BN = 64, BK = 16;
    __shared__ float As[BK][BM];
    __shared__ float Ws[BK][BN];
    int m0 = blockIdx.y * BM, n0 = blockIdx.x * BN;
    int tid = threadIdx.x;
    int tx = tid & 15, ty = tid >> 4;
    int lm = tid >> 2;          // 0..63 (row within tile for loads)
    int lk4 = (tid & 3) * 4;    // 0,4,8,12 (k within tile for loads)

    float acc[4][4] = {};

    for (int k0 = 0; k0 < K; k0 += BK) {
        float4 a4 = *(const float4*)&A[(size_t)(m0 + lm) * lda + k0 + lk4];
        As[lk4 + 0][lm] = a4.x; As[lk4 + 1][lm] = a4.y;
        As[lk4 + 2][lm] = a4.z; As[lk4 + 3][lm] = a4.w;
        float4 w4 = make_float4(0.f, 0.f, 0.f, 0.f);
        if (n0 + lm < N) w4 = *(const float4*)&W[(size_t)(n0 + lm) * K + k0 + lk4];
        Ws[lk4 + 0][lm] = w4.x; Ws[lk4 + 1][lm] = w4.y;
        Ws[lk4 + 2][lm] = w4.z; Ws[lk4 + 3][lm] = w4.w;
        __syncthreads();
        #pragma unroll
        for (int k = 0; k < BK; ++k) {
            float4 av = *(const float4*)&As[k][ty * 4];
            float4 wv = *(const float4*)&Ws[k][tx * 4];
            acc[0][0] = fmaf(av.x, wv.x, acc[0][0]);
            acc[0][1] = fmaf(av.x, wv.y, acc[0][1]);
            acc[0][2] = fmaf(av.x, wv.z, acc[0][2]);
            acc[0][3] = fmaf(av.x, wv.w, acc[0][3]);
            acc[1][0] = fmaf(av.y, wv.x, acc[1][0]);
            acc[1][1] = fmaf(av.y, wv.y, acc[1][1]);
            acc[1][2] = fmaf(av.y, wv.z, acc[1][2]);
            acc[1][3] = fmaf(av.y, wv.w, acc[1][3]);
            acc[2][0] = fmaf(av.z, wv.x, acc[2][0]);
            acc[2][1] = fmaf(av.z, wv.y, acc[2][1]);
            acc[2][2] = fmaf(av.z, wv.z, acc[2][2]);
            acc[2][3] = fmaf(av.z, wv.w, acc[2][3]);
            acc[3][0] = fmaf(av.w, wv.x, acc[3][0]);
            acc[3][1] = fmaf(av.w, wv.y, acc[3][1]);
            acc[3][2] = fmaf(av.w, wv.z, acc[3][2]);
            acc[3][3] = fmaf(av.w, wv.w, acc[3][3]);
        }
        __syncthreads();
    }

    #pragma unroll
    for (int r = 0; r < 4; ++r) {
        int row = m0 + ty * 4 + r;
        #pragma unroll
        for (int c = 0; c < 4; ++c) {
            int col = n0 + tx * 4 + c;
            if (col < N) {
                float v = acc[r][c];
                if (EPI == 0) {
                    C[(size_t)row * N + col] = v;
                } else if (EPI == 1) {
                    C[(size_t)row * N + col] += v;
                } else {  // softplus(v + bias)
                    v += bias[col];
                    float sp = fmaxf(v, 0.f) + log1pf(__expf(-fabsf(v)));
                    C[(size_t)row * N + col] = sp;
                }
            }
        }
    }
}

// -------------------- causal conv (K=4) + bias + silu --------------------
// reads xs part (first IDIM cols) of proj (row stride 2*IDIM)
__global__ __launch_bounds__(256) void conv_silu_kernel(const float* __restrict__ proj,
                                                        const float* __restrict__ cw,
                                                        const float* __restrict__ cb,
                                                        float* __restrict__ xs) {
    int idx = blockIdx.x * 256 + threadIdx.x;   // TOK*IDIM
    if (idx >= TOK * IDIM) return;
    int i = idx & (IDIM - 1);
    int tok = idx >> 9;
    int t = tok & (LSEQ - 1);
    const float* p = proj + (size_t)tok * (2 * IDIM) + i;
    float w0 = cw[i * 4 + 0], w1 = cw[i * 4 + 1], w2 = cw[i * 4 + 2], w3 = cw[i * 4 + 3];
    float acc = cb[i];
    acc = fmaf((t >= 3 ? p[-3 * 2 * IDIM] : 0.f), w0, acc);
    acc = fmaf((t >= 2 ? p[-2 * 2 * IDIM] : 0.f), w1, acc);
    acc = fmaf((t >= 1 ? p[-1 * 2 * IDIM] : 0.f), w2, acc);
    acc = fmaf(p[0], w3, acc);
    xs[idx] = acc / (1.f + __expf(-acc));   // silu
}

// -------------------- SSM scan --------------------
// thread layout: n = tid&15, i_local = tid>>4 (16 channels/block)
// grid: BATCH * (IDIM/16) = 128 blocks
__global__ __launch_bounds__(256) void scan_kernel(const float* __restrict__ ssm,
                                                   const float* __restrict__ dt,
                                                   const float* __restrict__ xs,
                                                   const float* __restrict__ proj,
                                                   const float* __restrict__ A_log,
                                                   const float* __restrict__ Dw,
                                                   float* __restrict__ y) {
    int n = threadIdx.x & 15;
    int il = threadIdx.x >> 4;
    int b = blockIdx.x >> 5;
    int i = (blockIdx.x & 31) * 16 + il;

    float A = -__expf(A_log[i * NST + n]);
    float Dv = Dw[i];
    float state = 0.f;

    const float* ssm_b = ssm + (size_t)b * LSEQ * 48;
    const float* dt_b  = dt  + (size_t)b * LSEQ * IDIM + i;
    const float* xs_b  = xs  + (size_t)b * LSEQ * IDIM + i;
    const float* g_b   = proj + (size_t)b * LSEQ * (2 * IDIM) + IDIM + i;
    float* y_b         = y   + (size_t)b * LSEQ * IDIM + i;

    for (int t = 0; t < LSEQ; ++t) {
        float dtv = dt_b[(size_t)t * IDIM];
        float xv  = xs_b[(size_t)t * IDIM];
        float Bv  = ssm_b[t * 48 + 16 + n];
        float Cv  = ssm_b[t * 48 + 32 + n];
        float dA  = __expf(dtv * A);
        state = fmaf(dA, state, dtv * xv * Bv);
        float py = state * Cv;
        py += __shfl_xor(py, 1, 64);
        py += __shfl_xor(py, 2, 64);
        py += __shfl_xor(py, 4, 64);
        py += __shfl_xor(py, 8, 64);
        if (n == 0) {
            float g = g_b[(size_t)t * (2 * IDIM)];
            float yv = (py + xv * Dv) * (g / (1.f + __expf(-g)));
            y_b[(size_t)t * IDIM] = yv;
        }
    }
}

// -------------------- final norm (pooled rows only) + MLP head --------------------
__global__ __launch_bounds__(256) void head_kernel(const float* __restrict__ h,
                                                   const int* __restrict__ lengths,
                                                   const float* __restrict__ fw,
                                                   const float* __restrict__ w1,
                                                   const float* __restrict__ b1,
                                                   const float* __restrict__ w2,
                                                   const float* __restrict__ b2,
                                                   float* __restrict__ out) {
    int b = blockIdx.x;
    int c = threadIdx.x;
    int len = lengths[b];
    const float* row = h + ((size_t)b * LSEQ + (len - 1)) * HDIM;
    float v = row[c];
    float s = v * v;
    #pragma unroll
    for (int m = 32; m >= 1; m >>= 1) s += __shfl_xor(s, m, 64);
    __shared__ float ls[4];
    __shared__ float pooled[HDIM];
    __shared__ float hd[64];
    if ((c & 63) == 0) ls[c >> 6] = s;
    __syncthreads();
    float tot = ls[0] + ls[1] + ls[2] + ls[3];
    float rstd = rsqrtf(tot * (1.0f / HDIM) + 1e-5f);
    pooled[c] = v * rstd * fw[c];
    __syncthreads();
    if (c < 64) {
        float a = b1[c];
        for (int k = 0; k < HDIM; ++k) a = fmaf(pooled[k], w1[c * HDIM + k], a);
        float g = 0.5f * a * (1.f + erff(a * 0.70710678118654752f));  // exact gelu
        hd[c] = g * w2[c];
    }
    __syncthreads();
    if (c == 0) {
        float o = b2[0];
        for (int k = 0; k < 64; ++k) o += hd[k];
        out[b] = o;
    }
}

extern "C" void kernel_launch(void* const* d_in, const int* in_sizes, int n_in,
                              void* d_out, int out_size, void* d_ws, size_t ws_size,
                              hipStream_t stream) {
    const int*   ids         = (const int*)d_in[0];
    const int*   lengths     = (const int*)d_in[1];
    const float* embed       = (const float*)d_in[2];
    const float* norm_w      = (const float*)d_in[3];
    const float* in_proj_w   = (const float*)d_in[4];
    const float* conv_w      = (const float*)d_in[5];
    const float* conv_b      = (const float*)d_in[6];
    const float* x_proj_w    = (const float*)d_in[7];
    const float* dt_proj_w   = (const float*)d_in[8];
    const float* dt_proj_b   = (const float*)d_in[9];
    const float* A_log       = (const float*)d_in[10];
    const float* Dw          = (const float*)d_in[11];
    const float* out_proj_w  = (const float*)d_in[12];
    const float* final_norm_w= (const float*)d_in[13];
    const float* head_w1     = (const float*)d_in[14];
    const float* head_b1     = (const float*)d_in[15];
    const float* head_w2     = (const float*)d_in[16];
    const float* head_b2     = (const float*)d_in[17];

    float* ws  = (float*)d_ws;
    float* h    = ws;                       // 4096*256  = 1,048,576
    float* x    = h    + 1048576;           // 4096*256
    float* proj = x    + 1048576;           // 4096*1024 = 4,194,304
    float* xs   = proj + 4194304;           // 4096*512  = 2,097,152
    float* ssm  = xs   + 2097152;           // 4096*48   =   196,608
    float* dt   = ssm  + 196608;            // 4096*512
    float* y    = dt   + 2097152;           // 4096*512

    embed_kernel<<<TOK * HDIM / 256, 256, 0, stream>>>(ids, embed, h);

    for (int l = 0; l < LAYERS; ++l) {
        rmsnorm_kernel<<<TOK, 256, 0, stream>>>(h, norm_w + l * HDIM, x);
        gemm_kernel<0><<<dim3(1024 / 64, TOK / 64), 256, 0, stream>>>(
            x, in_proj_w + (size_t)l * 2 * IDIM * HDIM, nullptr, proj, TOK, 2 * IDIM, HDIM, HDIM);
        conv_silu_kernel<<<TOK * IDIM / 256, 256, 0, stream>>>(
            proj, conv_w + l * IDIM * KCONV, conv_b + l * IDIM, xs);
        gemm_kernel<0><<<dim3(1, TOK / 64), 256, 0, stream>>>(
            xs, x_proj_w + (size_t)l * 48 * IDIM, nullptr, ssm, TOK, 48, IDIM, IDIM);
        gemm_kernel<2><<<dim3(IDIM / 64, TOK / 64), 256, 0, stream>>>(
            ssm, dt_proj_w + (size_t)l * IDIM * 16, dt_proj_b + l * IDIM, dt, TOK, IDIM, 16, 48);
        scan_kernel<<<BATCH * (IDIM / 16), 256, 0, stream>>>(
            ssm, dt, xs, proj, A_log + (size_t)l * IDIM * NST, Dw + l * IDIM, y);
        gemm_kernel<1><<<dim3(HDIM / 64, TOK / 64), 256, 0, stream>>>(
            y, out_proj_w + (size_t)l * HDIM * IDIM, nullptr, h, TOK, HDIM, IDIM, IDIM);
    }

    head_kernel<<<BATCH, 256, 0, stream>>>(h, lengths, final_norm_w,
                                           head_w1, head_b1, head_w2, head_b2,
                                           (float*)d_out);
}

// Round 2
// 1019.811 us; speedup vs baseline: 3.3776x; 3.3776x over previous
//
#include <hip/hip_runtime.h>
#include <hip/hip_bf16.h>

#define HDIM 256
#define IDIM 512
#define NST 16
#define KCONV 4
#define LAYERS 4
#define BATCH 4
#define LSEQ 1024
#define TOK (BATCH * LSEQ)   // 4096

// -------------------- embedding --------------------
__global__ __launch_bounds__(256) void embed_kernel(const int* __restrict__ ids,
                                                    const float* __restrict__ embed,
                                                    float* __restrict__ h) {
    int idx = blockIdx.x * 256 + threadIdx.x;          // TOK*HDIM = 1,048,576
    if (idx < TOK * HDIM) {
        int tok = idx >> 8;
        int c = idx & (HDIM - 1);
        h[idx] = embed[ids[tok] * HDIM + c];
    }
}

// -------------------- rmsnorm (per token row of H=256) --------------------
__global__ __launch_bounds__(256) void rmsnorm_kernel(const float* __restrict__ h,
                                                      const float* __restrict__ w,
                                                      float* __restrict__ x) {
    int tok = blockIdx.x;
    int c = threadIdx.x;
    float v = h[tok * HDIM + c];
    float s = v * v;
    #pragma unroll
    for (int m = 32; m >= 1; m >>= 1) s += __shfl_xor(s, m, 64);
    __shared__ float ls[4];
    __shared__ float rstd_s;
    int wid = threadIdx.x >> 6;
    if ((threadIdx.x & 63) == 0) ls[wid] = s;
    __syncthreads();
    if (threadIdx.x == 0) {
        float tot = ls[0] + ls[1] + ls[2] + ls[3];
        rstd_s = rsqrtf(tot * (1.0f / HDIM) + 1e-5f);
    }
    __syncthreads();
    x[tok * HDIM + c] = v * rstd_s * w[c];
}

// -------------------- generic tiled GEMM: C[M,N] = A[M,K(lda)] * W[N,K]^T --------------------
// EPI: 0 = store, 1 = accumulate into C (residual), 2 = softplus(acc + bias)
template <int EPI>
__global__ __launch_bounds__(256) void gemm_kernel(const float* __restrict__ A,
                                                   const float* __restrict__ W,
                                                   const float* __restrict__ bias,
                                                   float* __restrict__ C,
                                                   int M, int N, int K, int lda) {
    const int BM = 64, BN = 64, BK = 16;
    __shared__ float As[BK][BM];
    __shared__ float Ws[BK][BN];
    int m0 = blockIdx.y * BM, n0 = blockIdx.x * BN;
    int tid = threadIdx.x;
    int tx = tid & 15, ty = tid >> 4;
    int lm = tid >> 2;          // 0..63 (row within tile for loads)
    int lk4 = (tid & 3) * 4;    // 0,4,8,12 (k within tile for loads)

    float acc[4][4] = {};

    for (int k0 = 0; k0 < K; k0 += BK) {
        float4 a4 = *(const float4*)&A[(size_t)(m0 + lm) * lda + k0 + lk4];
        As[lk4 + 0][lm] = a4.x; As[lk4 + 1][lm] = a4.y;
        As[lk4 + 2][lm] = a4.z; As[lk4 + 3][lm] = a4.w;
        float4 w4 = make_float4(0.f, 0.f, 0.f, 0.f);
        if (n0 + lm < N) w4 = *(const float4*)&W[(size_t)(n0 + lm) * K + k0 + lk4];
        Ws[lk4 + 0][lm] = w4.x; Ws[lk4 + 1][lm] = w4.y;
        Ws[lk4 + 2][lm] = w4.z; Ws[lk4 + 3][lm] = w4.w;
        __syncthreads();
        #pragma unroll
        for (int k = 0; k < BK; ++k) {
            float4 av = *(const float4*)&As[k][ty * 4];
            float4 wv = *(const float4*)&Ws[k][tx * 4];
            acc[0][0] = fmaf(av.x, wv.x, acc[0][0]);
            acc[0][1] = fmaf(av.x, wv.y, acc[0][1]);
            acc[0][2] = fmaf(av.x, wv.z, acc[0][2]);
            acc[0][3] = fmaf(av.x, wv.w, acc[0][3]);
            acc[1][0] = fmaf(av.y, wv.x, acc[1][0]);
            acc[1][1] = fmaf(av.y, wv.y, acc[1][1]);
            acc[1][2] = fmaf(av.y, wv.z, acc[1][2]);
            acc[1][3] = fmaf(av.y, wv.w, acc[1][3]);
            acc[2][0] = fmaf(av.z, wv.x, acc[2][0]);
            acc[2][1] = fmaf(av.z, wv.y, acc[2][1]);
            acc[2][2] = fmaf(av.z, wv.z, acc[2][2]);
            acc[2][3] = fmaf(av.z, wv.w, acc[2][3]);
            acc[3][0] = fmaf(av.w, wv.x, acc[3][0]);
            acc[3][1] = fmaf(av.w, wv.y, acc[3][1]);
            acc[3][2] = fmaf(av.w, wv.z, acc[3][2]);
            acc[3][3] = fmaf(av.w, wv.w, acc[3][3]);
        }
        __syncthreads();
    }

    #pragma unroll
    for (int r = 0; r < 4; ++r) {
        int row = m0 + ty * 4 + r;
        #pragma unroll
        for (int c = 0; c < 4; ++c) {
            int col = n0 + tx * 4 + c;
            if (col < N) {
                float v = acc[r][c];
                if (EPI == 0) {
                    C[(size_t)row * N + col] = v;
                } else if (EPI == 1) {
                    C[(size_t)row * N + col] += v;
                } else {  // softplus(v + bias)
                    v += bias[col];
                    float sp = fmaxf(v, 0.f) + log1pf(__expf(-fabsf(v)));
                    C[(size_t)row * N + col] = sp;
                }
            }
        }
    }
}

// -------------------- causal conv (K=4) + bias + silu --------------------
__global__ __launch_bounds__(256) void conv_silu_kernel(const float* __restrict__ proj,
                                                        const float* __restrict__ cw,
                                                        const float* __restrict__ cb,
                                                        float* __restrict__ xs) {
    int idx = blockIdx.x * 256 + threadIdx.x;   // TOK*IDIM
    if (idx >= TOK * IDIM) return;
    int i = idx & (IDIM - 1);
    int tok = idx >> 9;
    int t = tok & (LSEQ - 1);
    const float* p = proj + (size_t)tok * (2 * IDIM) + i;
    float w0 = cw[i * 4 + 0], w1 = cw[i * 4 + 1], w2 = cw[i * 4 + 2], w3 = cw[i * 4 + 3];
    float acc = cb[i];
    acc = fmaf((t >= 3 ? p[-3 * 2 * IDIM] : 0.f), w0, acc);
    acc = fmaf((t >= 2 ? p[-2 * 2 * IDIM] : 0.f), w1, acc);
    acc = fmaf((t >= 1 ? p[-1 * 2 * IDIM] : 0.f), w2, acc);
    acc = fmaf(p[0], w3, acc);
    xs[idx] = acc / (1.f + __expf(-acc));   // silu
}

// -------------------- SSM scan: chunked two-pass linear-recurrence scan --------------------
// One block per (b, i): 256 threads = 16 time-chunks x 16 states.
// Phase 1: per-chunk (prod dA, end-state from zero init).
// Phase 2: 16-step serial scan over chunk summaries (16 threads).
// Phase 3: re-scan with corrected incoming state, reduce over n, emit y.
__global__ __launch_bounds__(256) void scan_kernel(const float* __restrict__ ssm,
                                                   const float* __restrict__ dt,
                                                   const float* __restrict__ xs,
                                                   const float* __restrict__ proj,
                                                   const float* __restrict__ A_log,
                                                   const float* __restrict__ Dw,
                                                   float* __restrict__ y) {
    const int LC = 64;   // chunk length
    const int NC = 16;   // number of chunks (LC*NC == LSEQ)
    int n = threadIdx.x & 15;
    int c = threadIdx.x >> 4;
    int b = blockIdx.x >> 9;          // blockIdx.x = b*IDIM + i
    int i = blockIdx.x & (IDIM - 1);

    float A = -__expf(A_log[i * NST + n]);

    __shared__ float aprodS[NC][17];
    __shared__ float stendS[NC][17];
    __shared__ float incS[NC][17];

    const float* ssm_b = ssm + (size_t)b * LSEQ * 48;
    const float* dt_b  = dt  + (size_t)b * LSEQ * IDIM + i;
    const float* xs_b  = xs  + (size_t)b * LSEQ * IDIM + i;

    int t0 = c * LC;

    // ---- phase 1 ----
    float aprod = 1.f, st = 0.f;
    for (int s = 0; s < LC; ++s) {
        int t = t0 + s;
        float dtv = dt_b[(size_t)t * IDIM];
        float xv  = xs_b[(size_t)t * IDIM];
        float Bv  = ssm_b[t * 48 + 16 + n];
        float dA  = __expf(dtv * A);
        aprod *= dA;
        st = fmaf(dA, st, dtv * xv * Bv);
    }
    aprodS[c][n] = aprod;
    stendS[c][n] = st;
    __syncthreads();

    // ---- phase 2: serial scan over chunks (one thread per n) ----
    if (threadIdx.x < 16) {
        int nn = threadIdx.x;
        float carry = 0.f;
        for (int cc = 0; cc < NC; ++cc) {
            incS[cc][nn] = carry;
            carry = fmaf(aprodS[cc][nn], carry, stendS[cc][nn]);
        }
    }
    __syncthreads();

    // ---- phase 3 ----
    st = incS[c][n];
    float Dv = Dw[i];
    const float* g_b = proj + (size_t)b * LSEQ * (2 * IDIM) + IDIM + i;
    float* y_b       = y    + (size_t)b * LSEQ * IDIM + i;

    for (int s = 0; s < LC; ++s) {
        int t = t0 + s;
        float dtv = dt_b[(size_t)t * IDIM];
        float xv  = xs_b[(size_t)t * IDIM];
        float Bv  = ssm_b[t * 48 + 16 + n];
        float Cv  = ssm_b[t * 48 + 32 + n];
        float dA  = __expf(dtv * A);
        st = fmaf(dA, st, dtv * xv * Bv);
        float py = st * Cv;
        py += __shfl_xor(py, 1, 64);
        py += __shfl_xor(py, 2, 64);
        py += __shfl_xor(py, 4, 64);
        py += __shfl_xor(py, 8, 64);
        if (n == 0) {
            float g = g_b[(size_t)t * (2 * IDIM)];
            float yv = (py + xv * Dv) * (g / (1.f + __expf(-g)));
            y_b[(size_t)t * IDIM] = yv;
        }
    }
}

// -------------------- final norm (pooled rows only) + MLP head --------------------
__global__ __launch_bounds__(256) void head_kernel(const float* __restrict__ h,
                                                   const int* __restrict__ lengths,
                                                   const float* __restrict__ fw,
                                                   const float* __restrict__ w1,
                                                   const float* __restrict__ b1,
                                                   const float* __restrict__ w2,
                                                   const float* __restrict__ b2,
                                                   float* __restrict__ out) {
    int b = blockIdx.x;
    int c = threadIdx.x;
    int len = lengths[b];
    const float* row = h + ((size_t)b * LSEQ + (len - 1)) * HDIM;
    float v = row[c];
    float s = v * v;
    #pragma unroll
    for (int m = 32; m >= 1; m >>= 1) s += __shfl_xor(s, m, 64);
    __shared__ float ls[4];
    __shared__ float pooled[HDIM];
    __shared__ float hd[64];
    if ((c & 63) == 0) ls[c >> 6] = s;
    __syncthreads();
    float tot = ls[0] + ls[1] + ls[2] + ls[3];
    float rstd = rsqrtf(tot * (1.0f / HDIM) + 1e-5f);
    pooled[c] = v * rstd * fw[c];
    __syncthreads();
    if (c < 64) {
        float a = b1[c];
        for (int k = 0; k < HDIM; ++k) a = fmaf(pooled[k], w1[c * HDIM + k], a);
        float g = 0.5f * a * (1.f + erff(a * 0.70710678118654752f));  // exact gelu
        hd[c] = g * w2[c];
    }
    __syncthreads();
    if (c == 0) {
        float o = b2[0];
        for (int k = 0; k < 64; ++k) o += hd[k];
        out[b] = o;
    }
}

extern "C" void kernel_launch(void* const* d_in, const int* in_sizes, int n_in,
                              void* d_out, int out_size, void* d_ws, size_t ws_size,
                              hipStream_t stream) {
    const int*   ids         = (const int*)d_in[0];
    const int*   lengths     = (const int*)d_in[1];
    const float* embed       = (const float*)d_in[2];
    const float* norm_w      = (const float*)d_in[3];
    const float* in_proj_w   = (const float*)d_in[4];
    const float* conv_w      = (const float*)d_in[5];
    const float* conv_b      = (const float*)d_in[6];
    const float* x_proj_w    = (const float*)d_in[7];
    const float* dt_proj_w   = (const float*)d_in[8];
    const float* dt_proj_b   = (const float*)d_in[9];
    const float* A_log       = (const float*)d_in[10];
    const float* Dw          = (const float*)d_in[11];
    const float* out_proj_w  = (const float*)d_in[12];
    const float* final_norm_w= (const float*)d_in[13];
    const float* head_w1     = (const float*)d_in[14];
    const float* head_b1     = (const float*)d_in[15];
    const float* head_w2     = (const float*)d_in[16];
    const float* head_b2     = (const float*)d_in[17];

    float* ws  = (float*)d_ws;
    float* h    = ws;                       // 4096*256  = 1,048,576
    float* x    = h    + 1048576;           // 4096*256
    float* proj = x    + 1048576;           // 4096*1024 = 4,194,304
    float* xs   = proj + 4194304;           // 4096*512  = 2,097,152
    float* ssm  = xs   + 2097152;           // 4096*48   =   196,608
    float* dt   = ssm  + 196608;            // 4096*512
    float* y    = dt   + 2097152;           // 4096*512

    embed_kernel<<<TOK * HDIM / 256, 256, 0, stream>>>(ids, embed, h);

    for (int l = 0; l < LAYERS; ++l) {
        rmsnorm_kernel<<<TOK, 256, 0, stream>>>(h, norm_w + l * HDIM, x);
        gemm_kernel<0><<<dim3(1024 / 64, TOK / 64), 256, 0, stream>>>(
            x, in_proj_w + (size_t)l * 2 * IDIM * HDIM, nullptr, proj, TOK, 2 * IDIM, HDIM, HDIM);
        conv_silu_kernel<<<TOK * IDIM / 256, 256, 0, stream>>>(
            proj, conv_w + l * IDIM * KCONV, conv_b + l * IDIM, xs);
        gemm_kernel<0><<<dim3(1, TOK / 64), 256, 0, stream>>>(
            xs, x_proj_w + (size_t)l * 48 * IDIM, nullptr, ssm, TOK, 48, IDIM, IDIM);
        gemm_kernel<2><<<dim3(IDIM / 64, TOK / 64), 256, 0, stream>>>(
            ssm, dt_proj_w + (size_t)l * IDIM * 16, dt_proj_b + l * IDIM, dt, TOK, IDIM, 16, 48);
        scan_kernel<<<BATCH * IDIM, 256, 0, stream>>>(
            ssm, dt, xs, proj, A_log + (size_t)l * IDIM * NST, Dw + l * IDIM, y);
        gemm_kernel<1><<<dim3(HDIM / 64, TOK / 64), 256, 0, stream>>>(
            y, out_proj_w + (size_t)l * HDIM * IDIM, nullptr, h, TOK, HDIM, IDIM, IDIM);
    }

    head_kernel<<<BATCH, 256, 0, stream>>>(h, lengths, final_norm_w,
                                           head_w1, head_b1, head_w2, head_b2,
                                           (float*)d_out);
}

// Round 3
// 809.788 us; speedup vs baseline: 4.2536x; 1.2594x over previous
//
#include <hip/hip_runtime.h>
#include <hip/hip_bf16.h>

#define HDIM 256
#define IDIM 512
#define NST 16
#define KCONV 4
#define LAYERS 4
#define BATCH 4
#define LSEQ 1024
#define TOK (BATCH * LSEQ)   // 4096

// -------------------- embedding --------------------
__global__ __launch_bounds__(256) void embed_kernel(const int* __restrict__ ids,
                                                    const float* __restrict__ embed,
                                                    float* __restrict__ h) {
    int idx = blockIdx.x * 256 + threadIdx.x;          // TOK*HDIM = 1,048,576
    if (idx < TOK * HDIM) {
        int tok = idx >> 8;
        int c = idx & (HDIM - 1);
        h[idx] = embed[ids[tok] * HDIM + c];
    }
}

// -------------------- rmsnorm (per token row of H=256) --------------------
__global__ __launch_bounds__(256) void rmsnorm_kernel(const float* __restrict__ h,
                                                      const float* __restrict__ w,
                                                      float* __restrict__ x) {
    int tok = blockIdx.x;
    int c = threadIdx.x;
    float v = h[tok * HDIM + c];
    float s = v * v;
    #pragma unroll
    for (int m = 32; m >= 1; m >>= 1) s += __shfl_xor(s, m, 64);
    __shared__ float ls[4];
    __shared__ float rstd_s;
    int wid = threadIdx.x >> 6;
    if ((threadIdx.x & 63) == 0) ls[wid] = s;
    __syncthreads();
    if (threadIdx.x == 0) {
        float tot = ls[0] + ls[1] + ls[2] + ls[3];
        rstd_s = rsqrtf(tot * (1.0f / HDIM) + 1e-5f);
    }
    __syncthreads();
    x[tok * HDIM + c] = v * rstd_s * w[c];
}

// -------------------- generic tiled GEMM: C[M,N] = A[M,K(lda)] * W[N,K]^T --------------------
// EPI: 0 = store, 1 = accumulate into C (residual), 2 = softplus(acc + bias)
template <int EPI>
__global__ __launch_bounds__(256) void gemm_kernel(const float* __restrict__ A,
                                                   const float* __restrict__ W,
                                                   const float* __restrict__ bias,
                                                   float* __restrict__ C,
                                                   int M, int N, int K, int lda) {
    const int BM = 64, BN = 64, BK = 16;
    __shared__ float As[BK][BM];
    __shared__ float Ws[BK][BN];
    int m0 = blockIdx.y * BM, n0 = blockIdx.x * BN;
    int tid = threadIdx.x;
    int tx = tid & 15, ty = tid >> 4;
    int lm = tid >> 2;          // 0..63 (row within tile for loads)
    int lk4 = (tid & 3) * 4;    // 0,4,8,12 (k within tile for loads)

    float acc[4][4] = {};

    for (int k0 = 0; k0 < K; k0 += BK) {
        float4 a4 = *(const float4*)&A[(size_t)(m0 + lm) * lda + k0 + lk4];
        As[lk4 + 0][lm] = a4.x; As[lk4 + 1][lm] = a4.y;
        As[lk4 + 2][lm] = a4.z; As[lk4 + 3][lm] = a4.w;
        float4 w4 = make_float4(0.f, 0.f, 0.f, 0.f);
        if (n0 + lm < N) w4 = *(const float4*)&W[(size_t)(n0 + lm) * K + k0 + lk4];
        Ws[lk4 + 0][lm] = w4.x; Ws[lk4 + 1][lm] = w4.y;
        Ws[lk4 + 2][lm] = w4.z; Ws[lk4 + 3][lm] = w4.w;
        __syncthreads();
        #pragma unroll
        for (int k = 0; k < BK; ++k) {
            float4 av = *(const float4*)&As[k][ty * 4];
            float4 wv = *(const float4*)&Ws[k][tx * 4];
            acc[0][0] = fmaf(av.x, wv.x, acc[0][0]);
            acc[0][1] = fmaf(av.x, wv.y, acc[0][1]);
            acc[0][2] = fmaf(av.x, wv.z, acc[0][2]);
            acc[0][3] = fmaf(av.x, wv.w, acc[0][3]);
            acc[1][0] = fmaf(av.y, wv.x, acc[1][0]);
            acc[1][1] = fmaf(av.y, wv.y, acc[1][1]);
            acc[1][2] = fmaf(av.y, wv.z, acc[1][2]);
            acc[1][3] = fmaf(av.y, wv.w, acc[1][3]);
            acc[2][0] = fmaf(av.z, wv.x, acc[2][0]);
            acc[2][1] = fmaf(av.z, wv.y, acc[2][1]);
            acc[2][2] = fmaf(av.z, wv.z, acc[2][2]);
            acc[2][3] = fmaf(av.z, wv.w, acc[2][3]);
            acc[3][0] = fmaf(av.w, wv.x, acc[3][0]);
            acc[3][1] = fmaf(av.w, wv.y, acc[3][1]);
            acc[3][2] = fmaf(av.w, wv.z, acc[3][2]);
            acc[3][3] = fmaf(av.w, wv.w, acc[3][3]);
        }
        __syncthreads();
    }

    #pragma unroll
    for (int r = 0; r < 4; ++r) {
        int row = m0 + ty * 4 + r;
        #pragma unroll
        for (int c = 0; c < 4; ++c) {
            int col = n0 + tx * 4 + c;
            if (col < N) {
                float v = acc[r][c];
                if (EPI == 0) {
                    C[(size_t)row * N + col] = v;
                } else if (EPI == 1) {
                    C[(size_t)row * N + col] += v;
                } else {  // softplus(v + bias)
                    v += bias[col];
                    float sp = fmaxf(v, 0.f) + log1pf(__expf(-fabsf(v)));
                    C[(size_t)row * N + col] = sp;
                }
            }
        }
    }
}

// -------------------- causal conv (K=4) + bias + silu --------------------
__global__ __launch_bounds__(256) void conv_silu_kernel(const float* __restrict__ proj,
                                                        const float* __restrict__ cw,
                                                        const float* __restrict__ cb,
                                                        float* __restrict__ xs) {
    int idx = blockIdx.x * 256 + threadIdx.x;   // TOK*IDIM
    if (idx >= TOK * IDIM) return;
    int i = idx & (IDIM - 1);
    int tok = idx >> 9;
    int t = tok & (LSEQ - 1);
    const float* p = proj + (size_t)tok * (2 * IDIM) + i;
    float w0 = cw[i * 4 + 0], w1 = cw[i * 4 + 1], w2 = cw[i * 4 + 2], w3 = cw[i * 4 + 3];
    float acc = cb[i];
    acc = fmaf((t >= 3 ? p[-3 * 2 * IDIM] : 0.f), w0, acc);
    acc = fmaf((t >= 2 ? p[-2 * 2 * IDIM] : 0.f), w1, acc);
    acc = fmaf((t >= 1 ? p[-1 * 2 * IDIM] : 0.f), w2, acc);
    acc = fmaf(p[0], w3, acc);
    xs[idx] = acc / (1.f + __expf(-acc));   // silu
}

// -------------------- SSM scan: chunked two-pass, XCD-swizzled, LDS-cached --------------------
// One block per (b, i): 256 threads = 16 time-chunks x 16 states.
// XCD swizzle: blocks sharing a cache line of channels land on the same XCD
// (per-XCD L2 working set ~3 MB < 4 MB), fixing the 6x HBM over-fetch.
// dt/xs staged in LDS during phase 1, reused in phase 3 (halves their traffic).
__global__ __launch_bounds__(256) void scan_kernel(const float* __restrict__ ssm,
                                                   const float* __restrict__ dt,
                                                   const float* __restrict__ xs,
                                                   const float* __restrict__ proj,
                                                   const float* __restrict__ A_log,
                                                   const float* __restrict__ Dw,
                                                   float* __restrict__ y) {
    const int LC = 64;   // chunk length
    const int NC = 16;   // number of chunks (LC*NC == LSEQ)
    int n = threadIdx.x & 15;
    int c = threadIdx.x >> 4;

    // XCD-aware swizzle: consecutive blockIdx round-robin across 8 XCDs, so
    // give XCD k the contiguous linear range [k*256, (k+1)*256).
    int lin = (blockIdx.x & 7) * 256 + (blockIdx.x >> 3);
    int b = lin >> 9;                 // lin = b*IDIM + i
    int i = lin & (IDIM - 1);

    float A = -__expf(A_log[i * NST + n]);

    __shared__ float dtS[NC][66];
    __shared__ float xsS[NC][66];
    __shared__ float aprodS[NC][17];
    __shared__ float stendS[NC][17];
    __shared__ float incS[NC][17];

    const float* ssm_b = ssm + (size_t)b * LSEQ * 48;
    const float* dt_b  = dt  + (size_t)b * LSEQ * IDIM + i;
    const float* xs_b  = xs  + (size_t)b * LSEQ * IDIM + i;

    int t0 = c * LC;

    // ---- stage dt/xs for this chunk into LDS (each element loaded once) ----
    #pragma unroll
    for (int j = 0; j < 4; ++j) {
        int s = n + 16 * j;
        size_t off = (size_t)(t0 + s) * IDIM;
        dtS[c][s] = dt_b[off];
        xsS[c][s] = xs_b[off];
    }
    __syncthreads();

    // ---- phase 1: per-chunk (prod dA, end state from zero init) ----
    float aprod = 1.f, st = 0.f;
    for (int s = 0; s < LC; ++s) {
        float dtv = dtS[c][s];
        float xv  = xsS[c][s];
        float Bv  = ssm_b[(t0 + s) * 48 + 16 + n];
        float dA  = __expf(dtv * A);
        aprod *= dA;
        st = fmaf(dA, st, dtv * xv * Bv);
    }
    aprodS[c][n] = aprod;
    stendS[c][n] = st;
    __syncthreads();

    // ---- phase 2: serial scan over chunk summaries (one thread per n) ----
    if (threadIdx.x < 16) {
        int nn = threadIdx.x;
        float carry = 0.f;
        for (int cc = 0; cc < NC; ++cc) {
            incS[cc][nn] = carry;
            carry = fmaf(aprodS[cc][nn], carry, stendS[cc][nn]);
        }
    }
    __syncthreads();

    // ---- phase 3: re-scan with corrected incoming state, emit y ----
    st = incS[c][n];
    float Dv = Dw[i];
    const float* g_b = proj + (size_t)b * LSEQ * (2 * IDIM) + IDIM + i;
    float* y_b       = y    + (size_t)b * LSEQ * IDIM + i;

    for (int s = 0; s < LC; ++s) {
        int t = t0 + s;
        float dtv = dtS[c][s];
        float xv  = xsS[c][s];
        float Bv  = ssm_b[t * 48 + 16 + n];
        float Cv  = ssm_b[t * 48 + 32 + n];
        float dA  = __expf(dtv * A);
        st = fmaf(dA, st, dtv * xv * Bv);
        float py = st * Cv;
        py += __shfl_xor(py, 1, 64);
        py += __shfl_xor(py, 2, 64);
        py += __shfl_xor(py, 4, 64);
        py += __shfl_xor(py, 8, 64);
        if (n == 0) {
            float g = g_b[(size_t)t * (2 * IDIM)];
            float yv = (py + xv * Dv) * (g / (1.f + __expf(-g)));
            y_b[(size_t)t * IDIM] = yv;
        }
    }
}

// -------------------- final norm (pooled rows only) + MLP head --------------------
__global__ __launch_bounds__(256) void head_kernel(const float* __restrict__ h,
                                                   const int* __restrict__ lengths,
                                                   const float* __restrict__ fw,
                                                   const float* __restrict__ w1,
                                                   const float* __restrict__ b1,
                                                   const float* __restrict__ w2,
                                                   const float* __restrict__ b2,
                                                   float* __restrict__ out) {
    int b = blockIdx.x;
    int c = threadIdx.x;
    int len = lengths[b];
    const float* row = h + ((size_t)b * LSEQ + (len - 1)) * HDIM;
    float v = row[c];
    float s = v * v;
    #pragma unroll
    for (int m = 32; m >= 1; m >>= 1) s += __shfl_xor(s, m, 64);
    __shared__ float ls[4];
    __shared__ float pooled[HDIM];
    __shared__ float hd[64];
    if ((c & 63) == 0) ls[c >> 6] = s;
    __syncthreads();
    float tot = ls[0] + ls[1] + ls[2] + ls[3];
    float rstd = rsqrtf(tot * (1.0f / HDIM) + 1e-5f);
    pooled[c] = v * rstd * fw[c];
    __syncthreads();
    if (c < 64) {
        float a = b1[c];
        for (int k = 0; k < HDIM; ++k) a = fmaf(pooled[k], w1[c * HDIM + k], a);
        float g = 0.5f * a * (1.f + erff(a * 0.70710678118654752f));  // exact gelu
        hd[c] = g * w2[c];
    }
    __syncthreads();
    if (c == 0) {
        float o = b2[0];
        for (int k = 0; k < 64; ++k) o += hd[k];
        out[b] = o;
    }
}

extern "C" void kernel_launch(void* const* d_in, const int* in_sizes, int n_in,
                              void* d_out, int out_size, void* d_ws, size_t ws_size,
                              hipStream_t stream) {
    const int*   ids         = (const int*)d_in[0];
    const int*   lengths     = (const int*)d_in[1];
    const float* embed       = (const float*)d_in[2];
    const float* norm_w      = (const float*)d_in[3];
    const float* in_proj_w   = (const float*)d_in[4];
    const float* conv_w      = (const float*)d_in[5];
    const float* conv_b      = (const float*)d_in[6];
    const float* x_proj_w    = (const float*)d_in[7];
    const float* dt_proj_w   = (const float*)d_in[8];
    const float* dt_proj_b   = (const float*)d_in[9];
    const float* A_log       = (const float*)d_in[10];
    const float* Dw          = (const float*)d_in[11];
    const float* out_proj_w  = (const float*)d_in[12];
    const float* final_norm_w= (const float*)d_in[13];
    const float* head_w1     = (const float*)d_in[14];
    const float* head_b1     = (const float*)d_in[15];
    const float* head_w2     = (const float*)d_in[16];
    const float* head_b2     = (const float*)d_in[17];

    float* ws  = (float*)d_ws;
    float* h    = ws;                       // 4096*256  = 1,048,576
    float* x    = h    + 1048576;           // 4096*256
    float* proj = x    + 1048576;           // 4096*1024 = 4,194,304
    float* xs   = proj + 4194304;           // 4096*512  = 2,097,152
    float* ssm  = xs   + 2097152;           // 4096*48   =   196,608
    float* dt   = ssm  + 196608;            // 4096*512
    float* y    = dt   + 2097152;           // 4096*512

    embed_kernel<<<TOK * HDIM / 256, 256, 0, stream>>>(ids, embed, h);

    for (int l = 0; l < LAYERS; ++l) {
        rmsnorm_kernel<<<TOK, 256, 0, stream>>>(h, norm_w + l * HDIM, x);
        gemm_kernel<0><<<dim3(1024 / 64, TOK / 64), 256, 0, stream>>>(
            x, in_proj_w + (size_t)l * 2 * IDIM * HDIM, nullptr, proj, TOK, 2 * IDIM, HDIM, HDIM);
        conv_silu_kernel<<<TOK * IDIM / 256, 256, 0, stream>>>(
            proj, conv_w + l * IDIM * KCONV, conv_b + l * IDIM, xs);
        gemm_kernel<0><<<dim3(1, TOK / 64), 256, 0, stream>>>(
            xs, x_proj_w + (size_t)l * 48 * IDIM, nullptr, ssm, TOK, 48, IDIM, IDIM);
        gemm_kernel<2><<<dim3(IDIM / 64, TOK / 64), 256, 0, stream>>>(
            ssm, dt_proj_w + (size_t)l * IDIM * 16, dt_proj_b + l * IDIM, dt, TOK, IDIM, 16, 48);
        scan_kernel<<<BATCH * IDIM, 256, 0, stream>>>(
            ssm, dt, xs, proj, A_log + (size_t)l * IDIM * NST, Dw + l * IDIM, y);
        gemm_kernel<1><<<dim3(HDIM / 64, TOK / 64), 256, 0, stream>>>(
            y, out_proj_w + (size_t)l * HDIM * IDIM, nullptr, h, TOK, HDIM, IDIM, IDIM);
    }

    head_kernel<<<BATCH, 256, 0, stream>>>(h, lengths, final_norm_w,
                                           head_w1, head_b1, head_w2, head_b2,
                                           (float*)d_out);
}

// Round 4
// 722.282 us; speedup vs baseline: 4.7689x; 1.1212x over previous
//
#include <hip/hip_runtime.h>
#include <hip/hip_bf16.h>

#define HDIM 256
#define IDIM 512
#define NST 16
#define KCONV 4
#define LAYERS 4
#define BATCH 4
#define LSEQ 1024
#define TOK (BATCH * LSEQ)   // 4096

// DPP butterfly add over each 16-lane row (all lanes end with the row sum).
// quad_perm xor1 = 0xB1, quad_perm xor2 = 0x4E, row_half_mirror = 0x141 (^7),
// row_mirror = 0x140 (^15). VALU-only: no LDS/ds_swizzle traffic.
#define DPP_ROW_ADD(p, CTRL)                                                   \
    p += __builtin_bit_cast(float, __builtin_amdgcn_update_dpp(                \
             0, __builtin_bit_cast(int, p), CTRL, 0xf, 0xf, false))

// -------------------- embedding --------------------
__global__ __launch_bounds__(256) void embed_kernel(const int* __restrict__ ids,
                                                    const float* __restrict__ embed,
                                                    float* __restrict__ h) {
    int idx = blockIdx.x * 256 + threadIdx.x;          // TOK*HDIM = 1,048,576
    if (idx < TOK * HDIM) {
        int tok = idx >> 8;
        int c = idx & (HDIM - 1);
        h[idx] = embed[ids[tok] * HDIM + c];
    }
}

// -------------------- rmsnorm (per token row of H=256) --------------------
__global__ __launch_bounds__(256) void rmsnorm_kernel(const float* __restrict__ h,
                                                      const float* __restrict__ w,
                                                      float* __restrict__ x) {
    int tok = blockIdx.x;
    int c = threadIdx.x;
    float v = h[tok * HDIM + c];
    float s = v * v;
    #pragma unroll
    for (int m = 32; m >= 1; m >>= 1) s += __shfl_xor(s, m, 64);
    __shared__ float ls[4];
    __shared__ float rstd_s;
    int wid = threadIdx.x >> 6;
    if ((threadIdx.x & 63) == 0) ls[wid] = s;
    __syncthreads();
    if (threadIdx.x == 0) {
        float tot = ls[0] + ls[1] + ls[2] + ls[3];
        rstd_s = rsqrtf(tot * (1.0f / HDIM) + 1e-5f);
    }
    __syncthreads();
    x[tok * HDIM + c] = v * rstd_s * w[c];
}

// -------------------- generic tiled GEMM: C[M,N] = A[M,K(lda)] * W[N,K]^T --------------------
// BM = 16*RM (RM = 4 or 2), BN = 64, BK = 16, 256 threads.
// EPI: 0 = store, 1 = accumulate into C (residual), 2 = softplus(acc + bias)
// Split-K via gridDim.z: each z-slice covers K/gridDim.z and writes to
// C + z*M*N (partials; caller reduces). Use EPI=0 when gridDim.z > 1.
template <int EPI, int RM>
__global__ __launch_bounds__(256) void gemm_kernel(const float* __restrict__ A,
                                                   const float* __restrict__ W,
                                                   const float* __restrict__ bias,
                                                   float* __restrict__ C,
                                                   int M, int N, int K, int lda) {
    const int BM = 16 * RM, BN = 64, BK = 16;
    __shared__ float As[BK][BM];
    __shared__ float Ws[BK][BN];
    int m0 = blockIdx.y * BM, n0 = blockIdx.x * BN;
    int tid = threadIdx.x;
    int tx = tid & 15, ty = tid >> 4;

    int kspl = K / gridDim.z;
    int kb = blockIdx.z * kspl;
    int ke = kb + kspl;
    if (gridDim.z > 1) C += (size_t)blockIdx.z * M * N;

    float acc[RM][4] = {};

    for (int k0 = kb; k0 < ke; k0 += BK) {
        if constexpr (RM == 4) {
            int lm = tid >> 2, lk = (tid & 3) * 4;
            float4 a4 = *(const float4*)&A[(size_t)(m0 + lm) * lda + k0 + lk];
            As[lk + 0][lm] = a4.x; As[lk + 1][lm] = a4.y;
            As[lk + 2][lm] = a4.z; As[lk + 3][lm] = a4.w;
        } else {
            int lm = tid >> 3, lk = (tid & 7) * 2;
            float2 a2 = *(const float2*)&A[(size_t)(m0 + lm) * lda + k0 + lk];
            As[lk + 0][lm] = a2.x; As[lk + 1][lm] = a2.y;
        }
        {
            int lm = tid >> 2, lk = (tid & 3) * 4;
            float4 w4 = make_float4(0.f, 0.f, 0.f, 0.f);
            if (n0 + lm < N) w4 = *(const float4*)&W[(size_t)(n0 + lm) * K + k0 + lk];
            Ws[lk + 0][lm] = w4.x; Ws[lk + 1][lm] = w4.y;
            Ws[lk + 2][lm] = w4.z; Ws[lk + 3][lm] = w4.w;
        }
        __syncthreads();
        #pragma unroll
        for (int k = 0; k < BK; ++k) {
            float4 wv = *(const float4*)&Ws[k][tx * 4];
            float ar[RM];
            if constexpr (RM == 4) {
                float4 av = *(const float4*)&As[k][ty * 4];
                ar[0] = av.x; ar[1] = av.y; ar[2] = av.z; ar[3] = av.w;
            } else {
                float2 av = *(const float2*)&As[k][ty * 2];
                ar[0] = av.x; ar[1] = av.y;
            }
            #pragma unroll
            for (int r = 0; r < RM; ++r) {
                acc[r][0] = fmaf(ar[r], wv.x, acc[r][0]);
                acc[r][1] = fmaf(ar[r], wv.y, acc[r][1]);
                acc[r][2] = fmaf(ar[r], wv.z, acc[r][2]);
                acc[r][3] = fmaf(ar[r], wv.w, acc[r][3]);
            }
        }
        __syncthreads();
    }

    #pragma unroll
    for (int r = 0; r < RM; ++r) {
        int row = m0 + ty * RM + r;
        #pragma unroll
        for (int cc = 0; cc < 4; ++cc) {
            int col = n0 + tx * 4 + cc;
            if (col < N) {
                float v = acc[r][cc];
                if (EPI == 0) {
                    C[(size_t)row * N + col] = v;
                } else if (EPI == 1) {
                    C[(size_t)row * N + col] += v;
                } else {  // softplus(v + bias)
                    v += bias[col];
                    float sp = fmaxf(v, 0.f) + log1pf(__expf(-fabsf(v)));
                    C[(size_t)row * N + col] = sp;
                }
            }
        }
    }
}

// -------------------- reduce 8 split-K partials of x_proj --------------------
// part: 8 slices of [TOK*48] floats; out: [TOK*48]
__global__ __launch_bounds__(256) void xreduce_kernel(const float* __restrict__ part,
                                                      float* __restrict__ out) {
    const int MN = TOK * 48;                 // 196608
    int j = (blockIdx.x * 256 + threadIdx.x) * 4;   // grid covers MN/4
    float4 s = *(const float4*)&part[j];
    #pragma unroll
    for (int z = 1; z < 8; ++z) {
        float4 p = *(const float4*)&part[(size_t)z * MN + j];
        s.x += p.x; s.y += p.y; s.z += p.z; s.w += p.w;
    }
    *(float4*)&out[j] = s;
}

// -------------------- causal conv (K=4) + bias + silu --------------------
__global__ __launch_bounds__(256) void conv_silu_kernel(const float* __restrict__ proj,
                                                        const float* __restrict__ cw,
                                                        const float* __restrict__ cb,
                                                        float* __restrict__ xs) {
    int idx = blockIdx.x * 256 + threadIdx.x;   // TOK*IDIM
    if (idx >= TOK * IDIM) return;
    int i = idx & (IDIM - 1);
    int tok = idx >> 9;
    int t = tok & (LSEQ - 1);
    const float* p = proj + (size_t)tok * (2 * IDIM) + i;
    float w0 = cw[i * 4 + 0], w1 = cw[i * 4 + 1], w2 = cw[i * 4 + 2], w3 = cw[i * 4 + 3];
    float acc = cb[i];
    acc = fmaf((t >= 3 ? p[-3 * 2 * IDIM] : 0.f), w0, acc);
    acc = fmaf((t >= 2 ? p[-2 * 2 * IDIM] : 0.f), w1, acc);
    acc = fmaf((t >= 1 ? p[-1 * 2 * IDIM] : 0.f), w2, acc);
    acc = fmaf(p[0], w3, acc);
    xs[idx] = acc / (1.f + __expf(-acc));   // silu
}

// -------------------- SSM scan: chunked two-pass, XCD-swizzled, DPP reduce --------------------
__global__ __launch_bounds__(256) void scan_kernel(const float* __restrict__ ssm,
                                                   const float* __restrict__ dt,
                                                   const float* __restrict__ xs,
                                                   const float* __restrict__ proj,
                                                   const float* __restrict__ A_log,
                                                   const float* __restrict__ Dw,
                                                   float* __restrict__ y) {
    const int LC = 64;   // chunk length
    const int NC = 16;   // number of chunks (LC*NC == LSEQ)
    int n = threadIdx.x & 15;
    int c = threadIdx.x >> 4;

    // XCD-aware swizzle: give XCD k the contiguous linear range [k*256,(k+1)*256)
    int lin = (blockIdx.x & 7) * 256 + (blockIdx.x >> 3);
    int b = lin >> 9;                 // lin = b*IDIM + i
    int i = lin & (IDIM - 1);

    float A = -__expf(A_log[i * NST + n]);

    __shared__ float dtS[NC][66];
    __shared__ float xsS[NC][66];
    __shared__ float aprodS[NC][17];
    __shared__ float stendS[NC][17];
    __shared__ float incS[NC][17];

    const float* ssm_b = ssm + (size_t)b * LSEQ * 48;
    const float* dt_b  = dt  + (size_t)b * LSEQ * IDIM + i;
    const float* xs_b  = xs  + (size_t)b * LSEQ * IDIM + i;

    int t0 = c * LC;

    // ---- stage dt/xs for this chunk into LDS (each element loaded once) ----
    #pragma unroll
    for (int j = 0; j < 4; ++j) {
        int s = n + 16 * j;
        size_t off = (size_t)(t0 + s) * IDIM;
        dtS[c][s] = dt_b[off];
        xsS[c][s] = xs_b[off];
    }
    __syncthreads();

    // ---- phase 1: per-chunk (prod dA, end state from zero init) ----
    float aprod = 1.f, st = 0.f;
    for (int s = 0; s < LC; ++s) {
        float dtv = dtS[c][s];
        float xv  = xsS[c][s];
        float Bv  = ssm_b[(t0 + s) * 48 + 16 + n];
        float dA  = __expf(dtv * A);
        aprod *= dA;
        st = fmaf(dA, st, dtv * xv * Bv);
    }
    aprodS[c][n] = aprod;
    stendS[c][n] = st;
    __syncthreads();

    // ---- phase 2: serial scan over chunk summaries (one thread per n) ----
    if (threadIdx.x < 16) {
        int nn = threadIdx.x;
        float carry = 0.f;
        for (int cc = 0; cc < NC; ++cc) {
            incS[cc][nn] = carry;
            carry = fmaf(aprodS[cc][nn], carry, stendS[cc][nn]);
        }
    }
    __syncthreads();

    // ---- phase 3: re-scan with corrected incoming state, emit y ----
    st = incS[c][n];
    float Dv = Dw[i];
    const float* g_b = proj + (size_t)b * LSEQ * (2 * IDIM) + IDIM + i;
    float* y_b       = y    + (size_t)b * LSEQ * IDIM + i;

    for (int s = 0; s < LC; ++s) {
        int t = t0 + s;
        float dtv = dtS[c][s];
        float xv  = xsS[c][s];
        float Bv  = ssm_b[t * 48 + 16 + n];
        float Cv  = ssm_b[t * 48 + 32 + n];
        float dA  = __expf(dtv * A);
        st = fmaf(dA, st, dtv * xv * Bv);
        float py = st * Cv;
        // butterfly sum over the 16-lane row: VALU-only DPP, no LDS
        DPP_ROW_ADD(py, 0xB1);   // xor 1 (quad_perm [1,0,3,2])
        DPP_ROW_ADD(py, 0x4E);   // xor 2 (quad_perm [2,3,0,1])
        DPP_ROW_ADD(py, 0x141);  // row_half_mirror (^7)
        DPP_ROW_ADD(py, 0x140);  // row_mirror (^15)
        if (n == 0) {
            float g = g_b[(size_t)t * (2 * IDIM)];
            float yv = (py + xv * Dv) * (g / (1.f + __expf(-g)));
            y_b[(size_t)t * IDIM] = yv;
        }
    }
}

// -------------------- final norm (pooled rows only) + MLP head --------------------
__global__ __launch_bounds__(256) void head_kernel(const float* __restrict__ h,
                                                   const int* __restrict__ lengths,
                                                   const float* __restrict__ fw,
                                                   const float* __restrict__ w1,
                                                   const float* __restrict__ b1,
                                                   const float* __restrict__ w2,
                                                   const float* __restrict__ b2,
                                                   float* __restrict__ out) {
    int b = blockIdx.x;
    int c = threadIdx.x;
    int len = lengths[b];
    const float* row = h + ((size_t)b * LSEQ + (len - 1)) * HDIM;
    float v = row[c];
    float s = v * v;
    #pragma unroll
    for (int m = 32; m >= 1; m >>= 1) s += __shfl_xor(s, m, 64);
    __shared__ float ls[4];
    __shared__ float pooled[HDIM];
    __shared__ float hd[64];
    if ((c & 63) == 0) ls[c >> 6] = s;
    __syncthreads();
    float tot = ls[0] + ls[1] + ls[2] + ls[3];
    float rstd = rsqrtf(tot * (1.0f / HDIM) + 1e-5f);
    pooled[c] = v * rstd * fw[c];
    __syncthreads();
    if (c < 64) {
        float a = b1[c];
        for (int k = 0; k < HDIM; ++k) a = fmaf(pooled[k], w1[c * HDIM + k], a);
        float g = 0.5f * a * (1.f + erff(a * 0.70710678118654752f));  // exact gelu
        hd[c] = g * w2[c];
    }
    __syncthreads();
    if (c == 0) {
        float o = b2[0];
        for (int k = 0; k < 64; ++k) o += hd[k];
        out[b] = o;
    }
}

extern "C" void kernel_launch(void* const* d_in, const int* in_sizes, int n_in,
                              void* d_out, int out_size, void* d_ws, size_t ws_size,
                              hipStream_t stream) {
    const int*   ids         = (const int*)d_in[0];
    const int*   lengths     = (const int*)d_in[1];
    const float* embed       = (const float*)d_in[2];
    const float* norm_w      = (const float*)d_in[3];
    const float* in_proj_w   = (const float*)d_in[4];
    const float* conv_w      = (const float*)d_in[5];
    const float* conv_b      = (const float*)d_in[6];
    const float* x_proj_w    = (const float*)d_in[7];
    const float* dt_proj_w   = (const float*)d_in[8];
    const float* dt_proj_b   = (const float*)d_in[9];
    const float* A_log       = (const float*)d_in[10];
    const float* Dw          = (const float*)d_in[11];
    const float* out_proj_w  = (const float*)d_in[12];
    const float* final_norm_w= (const float*)d_in[13];
    const float* head_w1     = (const float*)d_in[14];
    const float* head_b1     = (const float*)d_in[15];
    const float* head_w2     = (const float*)d_in[16];
    const float* head_b2     = (const float*)d_in[17];

    float* ws  = (float*)d_ws;
    float* h    = ws;                       // 4096*256  = 1,048,576
    float* x    = h    + 1048576;           // 4096*256
    float* proj = x    + 1048576;           // 4096*1024 = 4,194,304
    float* xs   = proj + 4194304;           // 4096*512  = 2,097,152
    float* ssm  = xs   + 2097152;           // 4096*48   =   196,608
    float* dt   = ssm  + 196608;            // 4096*512 (also holds x_proj split-K partials: 8*196608 <= 2,097,152)
    float* y    = dt   + 2097152;           // 4096*512

    embed_kernel<<<TOK * HDIM / 256, 256, 0, stream>>>(ids, embed, h);

    for (int l = 0; l < LAYERS; ++l) {
        rmsnorm_kernel<<<TOK, 256, 0, stream>>>(h, norm_w + l * HDIM, x);
        gemm_kernel<0, 4><<<dim3(1024 / 64, TOK / 64), 256, 0, stream>>>(
            x, in_proj_w + (size_t)l * 2 * IDIM * HDIM, nullptr, proj, TOK, 2 * IDIM, HDIM, HDIM);
        conv_silu_kernel<<<TOK * IDIM / 256, 256, 0, stream>>>(
            proj, conv_w + l * IDIM * KCONV, conv_b + l * IDIM, xs);
        // x_proj: split-K=8 into partials (dt buffer), then reduce into ssm
        gemm_kernel<0, 4><<<dim3(1, TOK / 64, 8), 256, 0, stream>>>(
            xs, x_proj_w + (size_t)l * 48 * IDIM, nullptr, dt, TOK, 48, IDIM, IDIM);
        xreduce_kernel<<<TOK * 48 / 4 / 256, 256, 0, stream>>>(dt, ssm);
        gemm_kernel<2, 4><<<dim3(IDIM / 64, TOK / 64), 256, 0, stream>>>(
            ssm, dt_proj_w + (size_t)l * IDIM * 16, dt_proj_b + l * IDIM, dt, TOK, IDIM, 16, 48);
        scan_kernel<<<BATCH * IDIM, 256, 0, stream>>>(
            ssm, dt, xs, proj, A_log + (size_t)l * IDIM * NST, Dw + l * IDIM, y);
        gemm_kernel<1, 2><<<dim3(HDIM / 64, TOK / 32), 256, 0, stream>>>(
            y, out_proj_w + (size_t)l * HDIM * IDIM, nullptr, h, TOK, HDIM, IDIM, IDIM);
    }

    head_kernel<<<BATCH, 256, 0, stream>>>(h, lengths, final_norm_w,
                                           head_w1, head_b1, head_w2, head_b2,
                                           (float*)d_out);
}

// Round 5
// 692.107 us; speedup vs baseline: 4.9768x; 1.0436x over previous
//
#include <hip/hip_runtime.h>
#include <hip/hip_bf16.h>

#define HDIM 256
#define IDIM 512
#define NST 16
#define KCONV 4
#define LAYERS 4
#define BATCH 4
#define LSEQ 1024
#define TOK (BATCH * LSEQ)   // 4096

typedef unsigned short u16;
typedef float f32x4 __attribute__((ext_vector_type(4)));
typedef short bf16x8 __attribute__((ext_vector_type(8)));

static __device__ __forceinline__ u16 f2bf(float f) {
    __hip_bfloat16 h = __float2bfloat16(f);
    return reinterpret_cast<u16&>(h);
}

// DPP butterfly add over each 16-lane row (all lanes end with the row sum).
#define DPP_ROW_ADD(p, CTRL)                                                   \
    p += __builtin_bit_cast(float, __builtin_amdgcn_update_dpp(                \
             0, __builtin_bit_cast(int, p), CTRL, 0xf, 0xf, false))

// -------------------- embedding --------------------
__global__ __launch_bounds__(256) void embed_kernel(const int* __restrict__ ids,
                                                    const float* __restrict__ embed,
                                                    float* __restrict__ h) {
    int idx = blockIdx.x * 256 + threadIdx.x;          // TOK*HDIM = 1,048,576
    if (idx < TOK * HDIM) {
        int tok = idx >> 8;
        int c = idx & (HDIM - 1);
        h[idx] = embed[ids[tok] * HDIM + c];
    }
}

// -------------------- f32 -> bf16 bulk convert (weights) --------------------
__global__ __launch_bounds__(256) void cvt_bf16_kernel(const float* __restrict__ in,
                                                       u16* __restrict__ out, int n) {
    int j = (blockIdx.x * 256 + threadIdx.x) * 4;
    if (j < n) {
        float4 v = *(const float4*)&in[j];
        unsigned lo = (unsigned)f2bf(v.x) | ((unsigned)f2bf(v.y) << 16);
        unsigned hi = (unsigned)f2bf(v.z) | ((unsigned)f2bf(v.w) << 16);
        *(uint2*)&out[j] = make_uint2(lo, hi);
    }
}

// -------------------- rmsnorm (per token row of H=256), bf16 out --------------------
__global__ __launch_bounds__(256) void rmsnorm_kernel(const float* __restrict__ h,
                                                      const float* __restrict__ w,
                                                      u16* __restrict__ xb) {
    int tok = blockIdx.x;
    int c = threadIdx.x;
    float v = h[tok * HDIM + c];
    float s = v * v;
    #pragma unroll
    for (int m = 32; m >= 1; m >>= 1) s += __shfl_xor(s, m, 64);
    __shared__ float ls[4];
    __shared__ float rstd_s;
    int wid = threadIdx.x >> 6;
    if ((threadIdx.x & 63) == 0) ls[wid] = s;
    __syncthreads();
    if (threadIdx.x == 0) {
        float tot = ls[0] + ls[1] + ls[2] + ls[3];
        rstd_s = rsqrtf(tot * (1.0f / HDIM) + 1e-5f);
    }
    __syncthreads();
    xb[tok * HDIM + c] = f2bf(v * rstd_s * w[c]);
}

// -------------------- bf16 MFMA GEMM: C[M,N](f32) = A[M,K](bf16) @ W[N,K](bf16)^T ----
// 128x128 block tile, 256 threads = 4 waves (2x2), each wave 64x64 via 4x4
// frags of v_mfma_f32_16x16x32_bf16. EPI: 0 = store, 1 = accumulate (residual).
template <int EPI>
__global__ __launch_bounds__(256) void gemm_bf16_kernel(const u16* __restrict__ A,
                                                        const u16* __restrict__ W,
                                                        float* __restrict__ C,
                                                        int M, int N, int K) {
    const int BM = 128, BK = 32;
    __shared__ __align__(16) u16 Al[BM][BK + 8];   // +8 elems: row stride 80B
    __shared__ __align__(16) u16 Bl[BM][BK + 8];
    int m0 = blockIdx.y * BM, n0 = blockIdx.x * BM;
    int tid = threadIdx.x;
    int lane = tid & 63;
    int wid = tid >> 6;
    int wr = wid >> 1, wc = wid & 1;   // 2x2 wave grid
    int r = lane & 15, g = lane >> 4;  // frag row/col = r, k-group = g

    f32x4 acc[4][4] = {};

    // staging: threads 0..127 own one A row, 128..255 one W row (32 bf16 = 64B each)
    int srow = tid & 127;
    const u16* src = (tid < 128) ? (A + (size_t)(m0 + srow) * K)
                                 : (W + (size_t)(n0 + srow) * K);
    u16* dstrow = (tid < 128) ? &Al[srow][0] : &Bl[srow][0];

    for (int k0 = 0; k0 < K; k0 += BK) {
        uint4 v0 = *(const uint4*)(src + k0);
        uint4 v1 = *(const uint4*)(src + k0 + 8);
        uint4 v2 = *(const uint4*)(src + k0 + 16);
        uint4 v3 = *(const uint4*)(src + k0 + 24);
        __syncthreads();                       // prior frag reads done
        *(uint4*)(dstrow)      = v0;
        *(uint4*)(dstrow + 8)  = v1;
        *(uint4*)(dstrow + 16) = v2;
        *(uint4*)(dstrow + 24) = v3;
        __syncthreads();

        bf16x8 af[4], bfr[4];
        #pragma unroll
        for (int f = 0; f < 4; ++f) {
            af[f]  = *(const bf16x8*)&Al[wr * 64 + f * 16 + r][g * 8];
            bfr[f] = *(const bf16x8*)&Bl[wc * 64 + f * 16 + r][g * 8];
        }
        #pragma unroll
        for (int fm = 0; fm < 4; ++fm)
            #pragma unroll
            for (int fn = 0; fn < 4; ++fn)
                acc[fm][fn] = __builtin_amdgcn_mfma_f32_16x16x32_bf16(
                    af[fm], bfr[fn], acc[fm][fn], 0, 0, 0);
    }

    // C/D layout: col = lane&15, row = (lane>>4)*4 + reg   [guide §3, m89]
    #pragma unroll
    for (int fm = 0; fm < 4; ++fm) {
        #pragma unroll
        for (int fn = 0; fn < 4; ++fn) {
            int col = n0 + wc * 64 + fn * 16 + r;
            #pragma unroll
            for (int v = 0; v < 4; ++v) {
                int row = m0 + wr * 64 + fm * 16 + g * 4 + v;
                if (EPI == 0) C[(size_t)row * N + col] = acc[fm][fn][v];
                else          C[(size_t)row * N + col] += acc[fm][fn][v];
            }
        }
    }
}

// -------------------- generic f32 tiled GEMM (kept for x_proj / dt_proj) ----------
// EPI: 0 = store, 2 = softplus(acc + bias). Split-K via gridDim.z (EPI=0).
template <int EPI>
__global__ __launch_bounds__(256) void gemm_kernel(const float* __restrict__ A,
                                                   const float* __restrict__ W,
                                                   const float* __restrict__ bias,
                                                   float* __restrict__ C,
                                                   int M, int N, int K, int lda) {
    const int BM = 64, BN = 64, BK = 16;
    __shared__ float As[BK][BM];
    __shared__ float Ws[BK][BN];
    int m0 = blockIdx.y * BM, n0 = blockIdx.x * BN;
    int tid = threadIdx.x;
    int tx = tid & 15, ty = tid >> 4;
    int lm = tid >> 2, lk = (tid & 3) * 4;

    int kspl = K / gridDim.z;
    int kb = blockIdx.z * kspl;
    int ke = kb + kspl;
    if (gridDim.z > 1) C += (size_t)blockIdx.z * M * N;

    float acc[4][4] = {};

    for (int k0 = kb; k0 < ke; k0 += BK) {
        float4 a4 = *(const float4*)&A[(size_t)(m0 + lm) * lda + k0 + lk];
        As[lk + 0][lm] = a4.x; As[lk + 1][lm] = a4.y;
        As[lk + 2][lm] = a4.z; As[lk + 3][lm] = a4.w;
        float4 w4 = make_float4(0.f, 0.f, 0.f, 0.f);
        if (n0 + lm < N) w4 = *(const float4*)&W[(size_t)(n0 + lm) * K + k0 + lk];
        Ws[lk + 0][lm] = w4.x; Ws[lk + 1][lm] = w4.y;
        Ws[lk + 2][lm] = w4.z; Ws[lk + 3][lm] = w4.w;
        __syncthreads();
        #pragma unroll
        for (int k = 0; k < BK; ++k) {
            float4 av = *(const float4*)&As[k][ty * 4];
            float4 wv = *(const float4*)&Ws[k][tx * 4];
            #pragma unroll
            for (int rr = 0; rr < 4; ++rr) {
                float ar = (&av.x)[rr];
                acc[rr][0] = fmaf(ar, wv.x, acc[rr][0]);
                acc[rr][1] = fmaf(ar, wv.y, acc[rr][1]);
                acc[rr][2] = fmaf(ar, wv.z, acc[rr][2]);
                acc[rr][3] = fmaf(ar, wv.w, acc[rr][3]);
            }
        }
        __syncthreads();
    }

    #pragma unroll
    for (int rr = 0; rr < 4; ++rr) {
        int row = m0 + ty * 4 + rr;
        #pragma unroll
        for (int cc = 0; cc < 4; ++cc) {
            int col = n0 + tx * 4 + cc;
            if (col < N) {
                float v = acc[rr][cc];
                if (EPI == 0) {
                    C[(size_t)row * N + col] = v;
                } else {  // softplus(v + bias)
                    v += bias[col];
                    float sp = fmaxf(v, 0.f) + log1pf(__expf(-fabsf(v)));
                    C[(size_t)row * N + col] = sp;
                }
            }
        }
    }
}

// -------------------- reduce 8 split-K partials of x_proj --------------------
__global__ __launch_bounds__(256) void xreduce_kernel(const float* __restrict__ part,
                                                      float* __restrict__ out) {
    const int MN = TOK * 48;                 // 196608
    int j = (blockIdx.x * 256 + threadIdx.x) * 4;
    float4 s = *(const float4*)&part[j];
    #pragma unroll
    for (int z = 1; z < 8; ++z) {
        float4 p = *(const float4*)&part[(size_t)z * MN + j];
        s.x += p.x; s.y += p.y; s.z += p.z; s.w += p.w;
    }
    *(float4*)&out[j] = s;
}

// -------------------- causal conv (K=4) + bias + silu --------------------
__global__ __launch_bounds__(256) void conv_silu_kernel(const float* __restrict__ proj,
                                                        const float* __restrict__ cw,
                                                        const float* __restrict__ cb,
                                                        float* __restrict__ xs) {
    int idx = blockIdx.x * 256 + threadIdx.x;   // TOK*IDIM
    if (idx >= TOK * IDIM) return;
    int i = idx & (IDIM - 1);
    int tok = idx >> 9;
    int t = tok & (LSEQ - 1);
    const float* p = proj + (size_t)tok * (2 * IDIM) + i;
    float w0 = cw[i * 4 + 0], w1 = cw[i * 4 + 1], w2 = cw[i * 4 + 2], w3 = cw[i * 4 + 3];
    float acc = cb[i];
    acc = fmaf((t >= 3 ? p[-3 * 2 * IDIM] : 0.f), w0, acc);
    acc = fmaf((t >= 2 ? p[-2 * 2 * IDIM] : 0.f), w1, acc);
    acc = fmaf((t >= 1 ? p[-1 * 2 * IDIM] : 0.f), w2, acc);
    acc = fmaf(p[0], w3, acc);
    xs[idx] = acc / (1.f + __expf(-acc));   // silu
}

// -------------------- SSM scan: chunked two-pass, unrolled, dA reg-cached --------
__global__ __launch_bounds__(256) void scan_kernel(const float* __restrict__ ssm,
                                                   const float* __restrict__ dt,
                                                   const float* __restrict__ xs,
                                                   const float* __restrict__ proj,
                                                   const float* __restrict__ A_log,
                                                   const float* __restrict__ Dw,
                                                   u16* __restrict__ yb) {
    const int LC = 64;   // chunk length
    const int NC = 16;   // number of chunks
    int n = threadIdx.x & 15;
    int c = threadIdx.x >> 4;

    // XCD-aware swizzle: give XCD k a contiguous channel range
    int lin = (blockIdx.x & 7) * 256 + (blockIdx.x >> 3);
    int b = lin >> 9;                 // lin = b*IDIM + i
    int i = lin & (IDIM - 1);

    float A = -__expf(A_log[i * NST + n]);

    __shared__ float dtS[NC][66];
    __shared__ float xsS[NC][66];
    __shared__ float aprodS[NC][17];
    __shared__ float stendS[NC][17];
    __shared__ float incS[NC][17];

    const float* ssm_b = ssm + (size_t)b * LSEQ * 48;
    const float* dt_b  = dt  + (size_t)b * LSEQ * IDIM + i;
    const float* xs_b  = xs  + (size_t)b * LSEQ * IDIM + i;

    int t0 = c * LC;
    const float* sb = ssm_b + (size_t)t0 * 48 + n;   // + s*48 per step

    // ---- stage dt/xs for this chunk into LDS ----
    #pragma unroll
    for (int j = 0; j < 4; ++j) {
        int s = n + 16 * j;
        size_t off = (size_t)(t0 + s) * IDIM;
        dtS[c][s] = dt_b[off];
        xsS[c][s] = xs_b[off];
    }
    __syncthreads();

    // ---- phase 1: per-chunk (prod dA, end state), cache dA in regs ----
    float dA_r[LC];
    float aprod = 1.f, st = 0.f;
    #pragma unroll
    for (int s = 0; s < LC; ++s) {
        float dtv = dtS[c][s];
        float xv  = xsS[c][s];
        float Bv  = sb[s * 48 + 16];
        float dA  = __expf(dtv * A);
        dA_r[s] = dA;
        aprod *= dA;
        st = fmaf(dA, st, dtv * xv * Bv);
    }
    aprodS[c][n] = aprod;
    stendS[c][n] = st;
    __syncthreads();

    // ---- phase 2: serial scan over chunk summaries ----
    if (threadIdx.x < 16) {
        int nn = threadIdx.x;
        float carry = 0.f;
        for (int cc = 0; cc < NC; ++cc) {
            incS[cc][nn] = carry;
            carry = fmaf(aprodS[cc][nn], carry, stendS[cc][nn]);
        }
    }
    __syncthreads();

    // ---- phase 3: re-scan with cached dA (no exp), emit y (bf16) ----
    st = incS[c][n];
    float Dv = Dw[i];
    const float* g_b = proj + (size_t)b * LSEQ * (2 * IDIM) + IDIM + i;
    u16* y_b         = yb   + (size_t)b * LSEQ * IDIM + i;

    #pragma unroll
    for (int s = 0; s < LC; ++s) {
        float dtv = dtS[c][s];
        float xv  = xsS[c][s];
        float Bv  = sb[s * 48 + 16];
        float Cv  = sb[s * 48 + 32];
        st = fmaf(dA_r[s], st, dtv * xv * Bv);
        float py = st * Cv;
        DPP_ROW_ADD(py, 0xB1);   // xor 1
        DPP_ROW_ADD(py, 0x4E);   // xor 2
        DPP_ROW_ADD(py, 0x141);  // ^7
        DPP_ROW_ADD(py, 0x140);  // ^15
        if (n == 0) {
            float g = g_b[(size_t)(t0 + s) * (2 * IDIM)];
            float yv = (py + xv * Dv) * (g / (1.f + __expf(-g)));
            y_b[(size_t)(t0 + s) * IDIM] = f2bf(yv);
        }
    }
}

// -------------------- final norm (pooled rows only) + MLP head --------------------
__global__ __launch_bounds__(256) void head_kernel(const float* __restrict__ h,
                                                   const int* __restrict__ lengths,
                                                   const float* __restrict__ fw,
                                                   const float* __restrict__ w1,
                                                   const float* __restrict__ b1,
                                                   const float* __restrict__ w2,
                                                   const float* __restrict__ b2,
                                                   float* __restrict__ out) {
    int b = blockIdx.x;
    int c = threadIdx.x;
    int len = lengths[b];
    const float* row = h + ((size_t)b * LSEQ + (len - 1)) * HDIM;
    float v = row[c];
    float s = v * v;
    #pragma unroll
    for (int m = 32; m >= 1; m >>= 1) s += __shfl_xor(s, m, 64);
    __shared__ float ls[4];
    __shared__ float pooled[HDIM];
    __shared__ float hd[64];
    if ((c & 63) == 0) ls[c >> 6] = s;
    __syncthreads();
    float tot = ls[0] + ls[1] + ls[2] + ls[3];
    float rstd = rsqrtf(tot * (1.0f / HDIM) + 1e-5f);
    pooled[c] = v * rstd * fw[c];
    __syncthreads();
    if (c < 64) {
        float a = b1[c];
        for (int k = 0; k < HDIM; ++k) a = fmaf(pooled[k], w1[c * HDIM + k], a);
        float g = 0.5f * a * (1.f + erff(a * 0.70710678118654752f));  // exact gelu
        hd[c] = g * w2[c];
    }
    __syncthreads();
    if (c == 0) {
        float o = b2[0];
        for (int k = 0; k < 64; ++k) o += hd[k];
        out[b] = o;
    }
}

extern "C" void kernel_launch(void* const* d_in, const int* in_sizes, int n_in,
                              void* d_out, int out_size, void* d_ws, size_t ws_size,
                              hipStream_t stream) {
    const int*   ids         = (const int*)d_in[0];
    const int*   lengths     = (const int*)d_in[1];
    const float* embed       = (const float*)d_in[2];
    const float* norm_w      = (const float*)d_in[3];
    const float* in_proj_w   = (const float*)d_in[4];
    const float* conv_w      = (const float*)d_in[5];
    const float* conv_b      = (const float*)d_in[6];
    const float* x_proj_w    = (const float*)d_in[7];
    const float* dt_proj_w   = (const float*)d_in[8];
    const float* dt_proj_b   = (const float*)d_in[9];
    const float* A_log       = (const float*)d_in[10];
    const float* Dw          = (const float*)d_in[11];
    const float* out_proj_w  = (const float*)d_in[12];
    const float* final_norm_w= (const float*)d_in[13];
    const float* head_w1     = (const float*)d_in[14];
    const float* head_b1     = (const float*)d_in[15];
    const float* head_w2     = (const float*)d_in[16];
    const float* head_b2     = (const float*)d_in[17];

    float* ws   = (float*)d_ws;
    float* h    = ws;                        // 1,048,576 f32
    float* proj = h    + 1048576;            // 4,194,304
    float* xs   = proj + 4194304;            // 2,097,152
    float* ssm  = xs   + 2097152;            //   196,608
    float* dtb  = ssm  + 196608;             // 2,097,152 (also x_proj split-K partials)
    u16* xb  = (u16*)(dtb + 2097152);        // 1,048,576 bf16
    u16* yb  = xb  + 1048576;                // 2,097,152 bf16
    u16* wib = yb  + 2097152;                // 1,048,576 bf16 (in_proj_w, all layers)
    u16* wob = wib + 1048576;                //   524,288 bf16 (out_proj_w, all layers)

    embed_kernel<<<TOK * HDIM / 256, 256, 0, stream>>>(ids, embed, h);
    cvt_bf16_kernel<<<1048576 / 4 / 256, 256, 0, stream>>>(in_proj_w, wib, 1048576);
    cvt_bf16_kernel<<<524288 / 4 / 256, 256, 0, stream>>>(out_proj_w, wob, 524288);

    for (int l = 0; l < LAYERS; ++l) {
        rmsnorm_kernel<<<TOK, 256, 0, stream>>>(h, norm_w + l * HDIM, xb);
        gemm_bf16_kernel<0><<<dim3(1024 / 128, TOK / 128), 256, 0, stream>>>(
            xb, wib + (size_t)l * 2 * IDIM * HDIM, proj, TOK, 2 * IDIM, HDIM);
        conv_silu_kernel<<<TOK * IDIM / 256, 256, 0, stream>>>(
            proj, conv_w + l * IDIM * KCONV, conv_b + l * IDIM, xs);
        // x_proj: split-K=8 into partials (dtb buffer), then reduce into ssm
        gemm_kernel<0><<<dim3(1, TOK / 64, 8), 256, 0, stream>>>(
            xs, x_proj_w + (size_t)l * 48 * IDIM, nullptr, dtb, TOK, 48, IDIM, IDIM);
        xreduce_kernel<<<TOK * 48 / 4 / 256, 256, 0, stream>>>(dtb, ssm);
        gemm_kernel<2><<<dim3(IDIM / 64, TOK / 64), 256, 0, stream>>>(
            ssm, dt_proj_w + (size_t)l * IDIM * 16, dt_proj_b + l * IDIM, dtb, TOK, IDIM, 16, 48);
        scan_kernel<<<BATCH * IDIM, 256, 0, stream>>>(
            ssm, dtb, xs, proj, A_log + (size_t)l * IDIM * NST, Dw + l * IDIM, yb);
        gemm_bf16_kernel<1><<<dim3(HDIM / 128, TOK / 128), 256, 0, stream>>>(
            yb, wob + (size_t)l * HDIM * IDIM, h, TOK, HDIM, IDIM);
    }

    head_kernel<<<BATCH, 256, 0, stream>>>(h, lengths, final_norm_w,
                                           head_w1, head_b1, head_w2, head_b2,
                                           (float*)d_out);
}

// Round 6
// 526.454 us; speedup vs baseline: 6.5428x; 1.3147x over previous
//
#include <hip/hip_runtime.h>
#include <hip/hip_bf16.h>

#define HDIM 256
#define IDIM 512
#define NST 16
#define KCONV 4
#define LAYERS 4
#define BATCH 4
#define LSEQ 1024
#define TOK (BATCH * LSEQ)   // 4096

typedef unsigned short u16;
typedef float f32x4 __attribute__((ext_vector_type(4)));
typedef short bf16x8 __attribute__((ext_vector_type(8)));

static __device__ __forceinline__ u16 f2bf(float f) {
    __hip_bfloat16 h = __float2bfloat16(f);
    return reinterpret_cast<u16&>(h);
}

// unpack bf16 #j (j=0..3) from a uint2 holding 4 packed bf16
static __device__ __forceinline__ float bfup(uint2 u, int j) {
    unsigned w = (j < 2) ? u.x : u.y;
    unsigned bits = (j & 1) ? (w & 0xffff0000u) : (w << 16);
    return __builtin_bit_cast(float, bits);
}

// DPP butterfly add over each 16-lane row (all lanes end with the row sum).
#define DPP_ROW_ADD(p, CTRL)                                                   \
    p += __builtin_bit_cast(float, __builtin_amdgcn_update_dpp(                \
             0, __builtin_bit_cast(int, p), CTRL, 0xf, 0xf, false))

// -------------------- embedding --------------------
__global__ __launch_bounds__(256) void embed_kernel(const int* __restrict__ ids,
                                                    const float* __restrict__ embed,
                                                    float* __restrict__ h) {
    int idx = blockIdx.x * 256 + threadIdx.x;          // TOK*HDIM = 1,048,576
    if (idx < TOK * HDIM) {
        int tok = idx >> 8;
        int c = idx & (HDIM - 1);
        h[idx] = embed[ids[tok] * HDIM + c];
    }
}

// -------------------- f32 -> bf16 bulk convert (weights) --------------------
__global__ __launch_bounds__(256) void cvt_bf16_kernel(const float* __restrict__ in,
                                                       u16* __restrict__ out, int n) {
    int j = (blockIdx.x * 256 + threadIdx.x) * 4;
    if (j < n) {
        float4 v = *(const float4*)&in[j];
        unsigned lo = (unsigned)f2bf(v.x) | ((unsigned)f2bf(v.y) << 16);
        unsigned hi = (unsigned)f2bf(v.z) | ((unsigned)f2bf(v.w) << 16);
        *(uint2*)&out[j] = make_uint2(lo, hi);
    }
}

// -------------------- rmsnorm (per token row of H=256), bf16 out --------------------
__global__ __launch_bounds__(256) void rmsnorm_kernel(const float* __restrict__ h,
                                                      const float* __restrict__ w,
                                                      u16* __restrict__ xb) {
    int tok = blockIdx.x;
    int c = threadIdx.x;
    float v = h[tok * HDIM + c];
    float s = v * v;
    #pragma unroll
    for (int m = 32; m >= 1; m >>= 1) s += __shfl_xor(s, m, 64);
    __shared__ float ls[4];
    __shared__ float rstd_s;
    int wid = threadIdx.x >> 6;
    if ((threadIdx.x & 63) == 0) ls[wid] = s;
    __syncthreads();
    if (threadIdx.x == 0) {
        float tot = ls[0] + ls[1] + ls[2] + ls[3];
        rstd_s = rsqrtf(tot * (1.0f / HDIM) + 1e-5f);
    }
    __syncthreads();
    xb[tok * HDIM + c] = f2bf(v * rstd_s * w[c]);
}

// -------------------- bf16 MFMA GEMM: C[M,N](f32) = A[M,K](bf16) @ W[N,K](bf16)^T ----
template <int EPI>
__global__ __launch_bounds__(256) void gemm_bf16_kernel(const u16* __restrict__ A,
                                                        const u16* __restrict__ W,
                                                        float* __restrict__ C,
                                                        int M, int N, int K) {
    const int BM = 128, BK = 32;
    __shared__ __align__(16) u16 Al[BM][BK + 8];
    __shared__ __align__(16) u16 Bl[BM][BK + 8];
    int m0 = blockIdx.y * BM, n0 = blockIdx.x * BM;
    int tid = threadIdx.x;
    int lane = tid & 63;
    int wid = tid >> 6;
    int wr = wid >> 1, wc = wid & 1;
    int r = lane & 15, g = lane >> 4;

    f32x4 acc[4][4] = {};

    int srow = tid & 127;
    const u16* src = (tid < 128) ? (A + (size_t)(m0 + srow) * K)
                                 : (W + (size_t)(n0 + srow) * K);
    u16* dstrow = (tid < 128) ? &Al[srow][0] : &Bl[srow][0];

    for (int k0 = 0; k0 < K; k0 += BK) {
        uint4 v0 = *(const uint4*)(src + k0);
        uint4 v1 = *(const uint4*)(src + k0 + 8);
        uint4 v2 = *(const uint4*)(src + k0 + 16);
        uint4 v3 = *(const uint4*)(src + k0 + 24);
        __syncthreads();
        *(uint4*)(dstrow)      = v0;
        *(uint4*)(dstrow + 8)  = v1;
        *(uint4*)(dstrow + 16) = v2;
        *(uint4*)(dstrow + 24) = v3;
        __syncthreads();

        bf16x8 af[4], bfr[4];
        #pragma unroll
        for (int f = 0; f < 4; ++f) {
            af[f]  = *(const bf16x8*)&Al[wr * 64 + f * 16 + r][g * 8];
            bfr[f] = *(const bf16x8*)&Bl[wc * 64 + f * 16 + r][g * 8];
        }
        #pragma unroll
        for (int fm = 0; fm < 4; ++fm)
            #pragma unroll
            for (int fn = 0; fn < 4; ++fn)
                acc[fm][fn] = __builtin_amdgcn_mfma_f32_16x16x32_bf16(
                    af[fm], bfr[fn], acc[fm][fn], 0, 0, 0);
    }

    #pragma unroll
    for (int fm = 0; fm < 4; ++fm) {
        #pragma unroll
        for (int fn = 0; fn < 4; ++fn) {
            int col = n0 + wc * 64 + fn * 16 + r;
            #pragma unroll
            for (int v = 0; v < 4; ++v) {
                int row = m0 + wr * 64 + fm * 16 + g * 4 + v;
                if (EPI == 0) C[(size_t)row * N + col] = acc[fm][fn][v];
                else          C[(size_t)row * N + col] += acc[fm][fn][v];
            }
        }
    }
}

// -------------------- generic f32 tiled GEMM --------------------
// C[M,N] = A[M,K(lda)] @ W[N,K(ldw)]^T
// EPI: 0 = store, 3 = softplus(acc + bias[row]).  Split-K via gridDim.z (EPI=0).
template <int EPI>
__global__ __launch_bounds__(256) void gemm_kernel(const float* __restrict__ A,
                                                   const float* __restrict__ W,
                                                   const float* __restrict__ bias,
                                                   float* __restrict__ C,
                                                   int M, int N, int K, int lda, int ldw) {
    const int BM = 64, BN = 64, BK = 16;
    __shared__ float As[BK][BM];
    __shared__ float Ws[BK][BN];
    int m0 = blockIdx.y * BM, n0 = blockIdx.x * BN;
    int tid = threadIdx.x;
    int tx = tid & 15, ty = tid >> 4;
    int lm = tid >> 2, lk = (tid & 3) * 4;

    int kspl = K / gridDim.z;
    int kb = blockIdx.z * kspl;
    int ke = kb + kspl;
    if (gridDim.z > 1) C += (size_t)blockIdx.z * M * N;

    float acc[4][4] = {};

    for (int k0 = kb; k0 < ke; k0 += BK) {
        float4 a4 = *(const float4*)&A[(size_t)(m0 + lm) * lda + k0 + lk];
        As[lk + 0][lm] = a4.x; As[lk + 1][lm] = a4.y;
        As[lk + 2][lm] = a4.z; As[lk + 3][lm] = a4.w;
        float4 w4 = make_float4(0.f, 0.f, 0.f, 0.f);
        if (n0 + lm < N) w4 = *(const float4*)&W[(size_t)(n0 + lm) * ldw + k0 + lk];
        Ws[lk + 0][lm] = w4.x; Ws[lk + 1][lm] = w4.y;
        Ws[lk + 2][lm] = w4.z; Ws[lk + 3][lm] = w4.w;
        __syncthreads();
        #pragma unroll
        for (int k = 0; k < BK; ++k) {
            float4 av = *(const float4*)&As[k][ty * 4];
            float4 wv = *(const float4*)&Ws[k][tx * 4];
            #pragma unroll
            for (int rr = 0; rr < 4; ++rr) {
                float ar = (&av.x)[rr];
                acc[rr][0] = fmaf(ar, wv.x, acc[rr][0]);
                acc[rr][1] = fmaf(ar, wv.y, acc[rr][1]);
                acc[rr][2] = fmaf(ar, wv.z, acc[rr][2]);
                acc[rr][3] = fmaf(ar, wv.w, acc[rr][3]);
            }
        }
        __syncthreads();
    }

    #pragma unroll
    for (int rr = 0; rr < 4; ++rr) {
        int row = m0 + ty * 4 + rr;
        #pragma unroll
        for (int cc = 0; cc < 4; ++cc) {
            int col = n0 + tx * 4 + cc;
            if (col < N) {
                float v = acc[rr][cc];
                if (EPI == 0) {
                    C[(size_t)row * N + col] = v;
                } else {  // softplus(v + bias[row])
                    v += bias[row];
                    float sp = fmaxf(v, 0.f) + log1pf(__expf(-fabsf(v)));
                    C[(size_t)row * N + col] = sp;
                }
            }
        }
    }
}

// -------------------- reduce 8 split-K partials of x_proj --------------------
__global__ __launch_bounds__(256) void xreduce_kernel(const float* __restrict__ part,
                                                      float* __restrict__ out) {
    const int MN = TOK * 48;                 // 196608
    int j = (blockIdx.x * 256 + threadIdx.x) * 4;
    float4 s = *(const float4*)&part[j];
    #pragma unroll
    for (int z = 1; z < 8; ++z) {
        float4 p = *(const float4*)&part[(size_t)z * MN + j];
        s.x += p.x; s.y += p.y; s.z += p.z; s.w += p.w;
    }
    *(float4*)&out[j] = s;
}

// -------------------- causal conv (K=4) + bias + silu, with transposed outputs ------
// 64t x 64i tile per block. Writes xs[tok][i] (f32, for x_proj GEMM) plus
// channel-major bf16 copies xs_T[i][tok] and gate_T[i][tok] (silu pre-applied)
// via an LDS transpose so the scan reads contiguous per-channel streams.
__global__ __launch_bounds__(256) void conv_silu_kernel(const float* __restrict__ proj,
                                                        const float* __restrict__ cw,
                                                        const float* __restrict__ cb,
                                                        float* __restrict__ xs,
                                                        u16* __restrict__ xs_T,
                                                        u16* __restrict__ gate_T) {
    __shared__ float tX[64][65];
    __shared__ float tG[64][65];
    int bidx = blockIdx.x;              // b*128 + tt*8 + it
    int b  = bidx >> 7;
    int tt = (bidx >> 3) & 15;
    int it = bidx & 7;
    int t0 = tt * 64, i0 = it * 64;
    int tr = threadIdx.x >> 6, ii = threadIdx.x & 63;
    int i = i0 + ii;
    float w0 = cw[i * 4 + 0], w1 = cw[i * 4 + 1], w2 = cw[i * 4 + 2], w3 = cw[i * 4 + 3];
    float bias = cb[i];

    #pragma unroll 4
    for (int r = 0; r < 16; ++r) {
        int tl = tr * 16 + r;
        int t = t0 + tl;
        const float* p = proj + ((size_t)(b * LSEQ + t)) * (2 * IDIM) + i;
        float acc = bias;
        acc = fmaf((t >= 3 ? p[-3 * 2 * IDIM] : 0.f), w0, acc);
        acc = fmaf((t >= 2 ? p[-2 * 2 * IDIM] : 0.f), w1, acc);
        acc = fmaf((t >= 1 ? p[-1 * 2 * IDIM] : 0.f), w2, acc);
        acc = fmaf(p[0], w3, acc);
        float xsv = acc / (1.f + __expf(-acc));
        xs[(size_t)(b * LSEQ + t) * IDIM + i] = xsv;
        tX[tl][ii] = xsv;
        float g = p[IDIM];
        tG[tl][ii] = g / (1.f + __expf(-g));
    }
    __syncthreads();
    #pragma unroll 4
    for (int r = 0; r < 16; ++r) {
        int il = tr * 16 + r;
        size_t off = (size_t)(i0 + il) * TOK + b * LSEQ + t0 + ii;
        xs_T[off]   = f2bf(tX[ii][il]);
        gate_T[off] = f2bf(tG[ii][il]);
    }
}

// -------------------- SSM scan: chunked two-pass, channel-major streams --------
// No LDS in the hot loops: dt_T/xs_T/gate_T are contiguous per (b,i) chunk.
__global__ __launch_bounds__(256) void scan_kernel(const float* __restrict__ ssm,
                                                   const float* __restrict__ dt_T,
                                                   const u16* __restrict__ xs_T,
                                                   const u16* __restrict__ gate_T,
                                                   const float* __restrict__ A_log,
                                                   const float* __restrict__ Dw,
                                                   u16* __restrict__ yb) {
    const int NC = 16;   // chunks of 64 steps
    int n = threadIdx.x & 15;
    int c = threadIdx.x >> 4;

    // XCD-aware swizzle: give XCD k a contiguous channel range
    int lin = (blockIdx.x & 7) * 256 + (blockIdx.x >> 3);
    int b = lin >> 9;                 // lin = b*IDIM + i
    int i = lin & (IDIM - 1);

    float A = -__expf(A_log[i * NST + n]);

    __shared__ float aprodS[NC][17];
    __shared__ float stendS[NC][17];
    __shared__ float incS[NC][17];

    int t0 = c * 64;
    size_t coff = (size_t)i * TOK + b * LSEQ + t0;
    const float4* dtp = (const float4*)(dt_T + coff);
    const uint2*  xsp = (const uint2*)(xs_T + coff);
    const uint2*  gp  = (const uint2*)(gate_T + coff);
    const float*  sb  = ssm + ((size_t)b * LSEQ + t0) * 48 + n;

    // ---- phase 1: per-chunk (prod dA, end state from zero init) ----
    float aprod = 1.f, st = 0.f;
    for (int q = 0; q < 16; ++q) {
        float4 d4 = dtp[q];
        uint2  xu = xsp[q];
        const float* sq = sb + q * 192;
        #pragma unroll
        for (int j = 0; j < 4; ++j) {
            float dtv = (&d4.x)[j];
            float xv  = bfup(xu, j);
            float Bv  = sq[j * 48 + 16];
            float dA  = __expf(dtv * A);
            aprod *= dA;
            st = fmaf(dA, st, dtv * xv * Bv);
        }
    }
    aprodS[c][n] = aprod;
    stendS[c][n] = st;
    __syncthreads();

    // ---- phase 2: serial scan over chunk summaries ----
    if (threadIdx.x < 16) {
        int nn = threadIdx.x;
        float carry = 0.f;
        for (int cc = 0; cc < NC; ++cc) {
            incS[cc][nn] = carry;
            carry = fmaf(aprodS[cc][nn], carry, stendS[cc][nn]);
        }
    }
    __syncthreads();

    // ---- phase 3: re-scan with corrected incoming state, emit y (bf16) ----
    st = incS[c][n];
    float Dv = Dw[i];
    u16* y_b = yb + ((size_t)b * LSEQ + t0) * IDIM + i;

    for (int q = 0; q < 16; ++q) {
        float4 d4 = dtp[q];
        uint2  xu = xsp[q];
        uint2  gu = gp[q];
        const float* sq = sb + q * 192;
        #pragma unroll
        for (int j = 0; j < 4; ++j) {
            float dtv = (&d4.x)[j];
            float xv  = bfup(xu, j);
            float Bv  = sq[j * 48 + 16];
            float Cv  = sq[j * 48 + 32];
            float dA  = __expf(dtv * A);
            st = fmaf(dA, st, dtv * xv * Bv);
            float py = st * Cv;
            DPP_ROW_ADD(py, 0xB1);   // xor 1
            DPP_ROW_ADD(py, 0x4E);   // xor 2
            DPP_ROW_ADD(py, 0x141);  // ^7
            DPP_ROW_ADD(py, 0x140);  // ^15
            if (n == 0) {
                float gv = bfup(gu, j);
                float yv = (py + xv * Dv) * gv;
                y_b[(size_t)(q * 4 + j) * IDIM] = f2bf(yv);
            }
        }
    }
}

// -------------------- final norm (pooled rows only) + MLP head --------------------
__global__ __launch_bounds__(256) void head_kernel(const float* __restrict__ h,
                                                   const int* __restrict__ lengths,
                                                   const float* __restrict__ fw,
                                                   const float* __restrict__ w1,
                                                   const float* __restrict__ b1,
                                                   const float* __restrict__ w2,
                                                   const float* __restrict__ b2,
                                                   float* __restrict__ out) {
    int b = blockIdx.x;
    int c = threadIdx.x;
    int len = lengths[b];
    const float* row = h + ((size_t)b * LSEQ + (len - 1)) * HDIM;
    float v = row[c];
    float s = v * v;
    #pragma unroll
    for (int m = 32; m >= 1; m >>= 1) s += __shfl_xor(s, m, 64);
    __shared__ float ls[4];
    __shared__ float pooled[HDIM];
    __shared__ float hd[64];
    if ((c & 63) == 0) ls[c >> 6] = s;
    __syncthreads();
    float tot = ls[0] + ls[1] + ls[2] + ls[3];
    float rstd = rsqrtf(tot * (1.0f / HDIM) + 1e-5f);
    pooled[c] = v * rstd * fw[c];
    __syncthreads();
    if (c < 64) {
        float a = b1[c];
        for (int k = 0; k < HDIM; ++k) a = fmaf(pooled[k], w1[c * HDIM + k], a);
        float g = 0.5f * a * (1.f + erff(a * 0.70710678118654752f));  // exact gelu
        hd[c] = g * w2[c];
    }
    __syncthreads();
    if (c == 0) {
        float o = b2[0];
        for (int k = 0; k < 64; ++k) o += hd[k];
        out[b] = o;
    }
}

extern "C" void kernel_launch(void* const* d_in, const int* in_sizes, int n_in,
                              void* d_out, int out_size, void* d_ws, size_t ws_size,
                              hipStream_t stream) {
    const int*   ids         = (const int*)d_in[0];
    const int*   lengths     = (const int*)d_in[1];
    const float* embed       = (const float*)d_in[2];
    const float* norm_w      = (const float*)d_in[3];
    const float* in_proj_w   = (const float*)d_in[4];
    const float* conv_w      = (const float*)d_in[5];
    const float* conv_b      = (const float*)d_in[6];
    const float* x_proj_w    = (const float*)d_in[7];
    const float* dt_proj_w   = (const float*)d_in[8];
    const float* dt_proj_b   = (const float*)d_in[9];
    const float* A_log       = (const float*)d_in[10];
    const float* Dw          = (const float*)d_in[11];
    const float* out_proj_w  = (const float*)d_in[12];
    const float* final_norm_w= (const float*)d_in[13];
    const float* head_w1     = (const float*)d_in[14];
    const float* head_b1     = (const float*)d_in[15];
    const float* head_w2     = (const float*)d_in[16];
    const float* head_b2     = (const float*)d_in[17];

    float* ws   = (float*)d_ws;
    float* h    = ws;                        // 1,048,576 f32
    float* proj = h    + 1048576;            // 4,194,304 f32
    float* xs   = proj + 4194304;            // 2,097,152 f32
    float* ssm  = xs   + 2097152;            //   196,608 f32
    float* dtb  = ssm  + 196608;             // 2,097,152 f32 (x_proj split-K partials, then dt_T)
    u16* xb  = (u16*)(dtb + 2097152);        // 1,048,576 bf16
    u16* yb  = xb  + 1048576;                // 2,097,152 bf16
    u16* wib = yb  + 2097152;                // 1,048,576 bf16 (in_proj_w)
    u16* wob = wib + 1048576;                //   524,288 bf16 (out_proj_w)
    u16* xsT = wob + 524288;                 // 2,097,152 bf16 (xs channel-major)
    u16* gT  = xsT + 2097152;                // 2,097,152 bf16 (silu(gate) channel-major)

    embed_kernel<<<TOK * HDIM / 256, 256, 0, stream>>>(ids, embed, h);
    cvt_bf16_kernel<<<1048576 / 4 / 256, 256, 0, stream>>>(in_proj_w, wib, 1048576);
    cvt_bf16_kernel<<<524288 / 4 / 256, 256, 0, stream>>>(out_proj_w, wob, 524288);

    for (int l = 0; l < LAYERS; ++l) {
        rmsnorm_kernel<<<TOK, 256, 0, stream>>>(h, norm_w + l * HDIM, xb);
        gemm_bf16_kernel<0><<<dim3(1024 / 128, TOK / 128), 256, 0, stream>>>(
            xb, wib + (size_t)l * 2 * IDIM * HDIM, proj, TOK, 2 * IDIM, HDIM);
        conv_silu_kernel<<<512, 256, 0, stream>>>(
            proj, conv_w + l * IDIM * KCONV, conv_b + l * IDIM, xs, xsT, gT);
        // x_proj: split-K=8 into partials (dtb), then reduce into ssm
        gemm_kernel<0><<<dim3(1, TOK / 64, 8), 256, 0, stream>>>(
            xs, x_proj_w + (size_t)l * 48 * IDIM, nullptr, dtb, TOK, 48, IDIM, IDIM, IDIM);
        xreduce_kernel<<<TOK * 48 / 4 / 256, 256, 0, stream>>>(dtb, ssm);
        // dt_T[i][tok] = softplus(dt_w @ ssm[:, :16]^T + b[i]) — transposed GEMM:
        // A = dt_proj_w [512][16], W-role = ssm [4096][48] (reads cols 0..15)
        gemm_kernel<3><<<dim3(TOK / 64, IDIM / 64), 256, 0, stream>>>(
            dt_proj_w + (size_t)l * IDIM * 16, ssm, dt_proj_b + l * IDIM, dtb,
            IDIM, TOK, 16, 16, 48);
        scan_kernel<<<BATCH * IDIM, 256, 0, stream>>>(
            ssm, dtb, xsT, gT, A_log + (size_t)l * IDIM * NST, Dw + l * IDIM, yb);
        gemm_bf16_kernel<1><<<dim3(HDIM / 128, TOK / 128), 256, 0, stream>>>(
            yb, wob + (size_t)l * HDIM * IDIM, h, TOK, HDIM, IDIM);
    }

    head_kernel<<<BATCH, 256, 0, stream>>>(h, lengths, final_norm_w,
                                           head_w1, head_b1, head_w2, head_b2,
                                           (float*)d_out);
}